// Round 7
// baseline (788.423 us; speedup 1.0000x reference)
//
#include <hip/hip_runtime.h>
#include <hip/hip_bf16.h>

#define HC   256   // H * C
#define FIN  32
#define NH   8

typedef __hip_bfloat16 bf16;

// ---------------- CSR build ---------------------------------------------------
__global__ void count_kernel(const int* __restrict__ dst, int* __restrict__ cnt, int E_) {
  int e = blockIdx.x * blockDim.x + threadIdx.x;
  if (e < E_) atomicAdd(&cnt[dst[e]], 1);
}

__global__ void scan_kernel(const int* __restrict__ cnt, int* __restrict__ rowptr,
                            int* __restrict__ fill, int N_, int E_) {
  __shared__ int part[1024];
  int t = threadIdx.x;
  int chunk = (N_ + 1023) / 1024;
  int lo = t * chunk, hi = lo + chunk;
  if (lo > N_) lo = N_;
  if (hi > N_) hi = N_;
  int s = 0;
  for (int i = lo; i < hi; ++i) s += cnt[i];
  part[t] = s;
  __syncthreads();
  for (int off = 1; off < 1024; off <<= 1) {
    int v = (t >= off) ? part[t - off] : 0;
    __syncthreads();
    part[t] += v;
    __syncthreads();
  }
  int run = part[t] - s;
  for (int i = lo; i < hi; ++i) { rowptr[i] = run; fill[i] = run; run += cnt[i]; }
  if (t == 0) rowptr[N_] = E_;
}

// ---- fold: M_l[8x8] = We_l x a_e_l ; P_ls/P_ld[32x8] = W_l x a_{src/dst}_l ----
// Mbuf layout (floats): [0:64) M1 | [64:128) M2 | [128:384) P1s | [384:640) P1d
//                       | [640:896) P2s | [896:1152) P2d
__global__ void fold_kernel(const float* __restrict__ We1, const float* __restrict__ ae1,
                            const float* __restrict__ We2, const float* __restrict__ ae2,
                            const float* __restrict__ W1, const float* __restrict__ as1,
                            const float* __restrict__ ad1,
                            const float* __restrict__ W2, const float* __restrict__ as2,
                            const float* __restrict__ ad2,
                            float* __restrict__ M) {
  for (int idx = threadIdx.x; idx < 1152; idx += 256) {
    const float* A; const float* V; int i;
    if (idx < 64)       { i = idx;       A = We1; V = ae1; }
    else if (idx < 128) { i = idx - 64;  A = We2; V = ae2; }
    else if (idx < 384) { i = idx - 128; A = W1;  V = as1; }
    else if (idx < 640) { i = idx - 384; A = W1;  V = ad1; }
    else if (idx < 896) { i = idx - 640; A = W2;  V = as2; }
    else                { i = idx - 896; A = W2;  V = ad2; }
    int k = i >> 3, h = i & 7;
    float s = 0.f;
    for (int c = 0; c < FIN; ++c)
      s = fmaf(A[k * HC + h * FIN + c], V[h * FIN + c], s);
    M[idx] = s;
  }
}

// ---- scatter into CSR order + pre-fold edge_attr@M for both layers ----------
__global__ void scatter_kernel(const int* __restrict__ src, const int* __restrict__ dst,
                               int* __restrict__ fill, const float* __restrict__ edge_attr,
                               const float* __restrict__ Mg,
                               int* __restrict__ srcs, int* __restrict__ dsts,
                               float* __restrict__ eal1, float* __restrict__ eal2, int E_) {
  __shared__ float Ms[128];
  if (threadIdx.x < 128) Ms[threadIdx.x] = Mg[threadIdx.x];
  __syncthreads();
  int e = blockIdx.x * blockDim.x + threadIdx.x;
  if (e >= E_) return;
  int d = dst[e];
  int pos = atomicAdd(&fill[d], 1);
  srcs[pos] = src[e];
  dsts[pos] = d;
  const float4* eap = (const float4*)(edge_attr + (size_t)e * NH);
  float4 ea0 = eap[0], ea1 = eap[1];
  float ea[NH] = {ea0.x, ea0.y, ea0.z, ea0.w, ea1.x, ea1.y, ea1.z, ea1.w};
  float o1[NH], o2[NH];
#pragma unroll
  for (int h = 0; h < NH; ++h) {
    float s1 = 0.f, s2 = 0.f;
#pragma unroll
    for (int k = 0; k < NH; ++k) {
      s1 = fmaf(ea[k], Ms[k * NH + h], s1);
      s2 = fmaf(ea[k], Ms[64 + k * NH + h], s2);
    }
    o1[h] = s1; o2[h] = s2;
  }
  float4* p1 = (float4*)(eal1 + (size_t)pos * NH);
  float4* p2 = (float4*)(eal2 + (size_t)pos * NH);
  p1[0] = make_float4(o1[0], o1[1], o1[2], o1[3]);
  p1[1] = make_float4(o1[4], o1[5], o1[6], o1[7]);
  p2[0] = make_float4(o2[0], o2[1], o2[2], o2[3]);
  p2[1] = make_float4(o2[4], o2[5], o2[6], o2[7]);
}

// ---- layer-1 prep: xq1 = bf16(emb[node_ids]); alsrc1/aldst1 = x @ P1 --------
__global__ __launch_bounds__(256) void
prep1_kernel(const float* __restrict__ emb, const int* __restrict__ node_ids,
             const float* __restrict__ P,   // [0:256) Ps | [256:512) Pd
             bf16* __restrict__ xq, float* __restrict__ alsrc,
             float* __restrict__ aldst, int N_) {
  __shared__ float xs[8][33];
  int t = threadIdx.x, n0 = blockIdx.x * 8;
  int nl = t >> 5, c = t & 31;
  int n = n0 + nl;
  if (n < N_) {
    float v = emb[(size_t)node_ids[n] * FIN + c];
    xq[(size_t)n * FIN + c] = __float2bfloat16(v);
    xs[nl][c] = v;
  }
  __syncthreads();
  if (t < 64) {
    int nl2 = t >> 3, h = t & 7;
    int n2 = n0 + nl2;
    if (n2 < N_) {
      float sa = 0.f, sd = 0.f;
#pragma unroll
      for (int k = 0; k < FIN; ++k) {
        float x = xs[nl2][k];
        sa = fmaf(x, P[k * 8 + h], sa);
        sd = fmaf(x, P[256 + k * 8 + h], sd);
      }
      alsrc[(size_t)n2 * NH + h] = sa;
      aldst[(size_t)n2 * NH + h] = sd;
    }
  }
}

// ---- per-CSR-position: ex = exp(leaky_relu(eal + alsrc[s] + aldst[d])) ------
__global__ void edge_kernel(const int* __restrict__ srcs, const int* __restrict__ dsts,
                            const float* __restrict__ eal,
                            const float* __restrict__ alsrc, const float* __restrict__ aldst,
                            float* __restrict__ ex_s, int E_) {
  int j = blockIdx.x * blockDim.x + threadIdx.x;
  if (j >= E_) return;
  int s = srcs[j], d = dsts[j];
  const float4* ep  = (const float4*)(eal + (size_t)j * NH);
  const float4* asp = (const float4*)(alsrc + (size_t)s * NH);
  const float4* adp = (const float4*)(aldst + (size_t)d * NH);
  float4 e0 = ep[0], e1 = ep[1];
  float4 as0 = asp[0], as1 = asp[1];
  float4 ad0 = adp[0], ad1 = adp[1];
  float ee[NH]  = {e0.x, e0.y, e0.z, e0.w, e1.x, e1.y, e1.z, e1.w};
  float als[NH] = {as0.x, as0.y, as0.z, as0.w, as1.x, as1.y, as1.z, as1.w};
  float ald[NH] = {ad0.x, ad0.y, ad0.z, ad0.w, ad1.x, ad1.y, ad1.z, ad1.w};
  float out[NH];
#pragma unroll
  for (int h = 0; h < NH; ++h) {
    float a = ee[h] + als[h] + ald[h];
    a = (a >= 0.f) ? a : 0.2f * a;
    out[h] = __expf(a);
  }
  float4* exp4 = (float4*)(ex_s + (size_t)j * NH);
  exp4[0] = make_float4(out[0], out[1], out[2], out[3]);
  exp4[1] = make_float4(out[4], out[5], out[6], out[7]);
}

// ---- fused agg: z[n,h,k]=Σ w·x[src,k]; out=relu(zW+b); x'=out@Wlin+blin -----
// 4 nodes per block; thread t owns (h=t>>5, k=t&31).
template <int K, int LOG2K, bool LOGITS>
__global__ __launch_bounds__(256) void
agg_kernel(const int* __restrict__ rowptr, const int* __restrict__ srcs,
           const float* __restrict__ ex_s, const bf16* __restrict__ xq,
           const float* __restrict__ W, const float* __restrict__ b,
           const float* __restrict__ Wlin, const float* __restrict__ blin,
           float* __restrict__ xoutf, bf16* __restrict__ xqn,
           const float* __restrict__ Pn,   // [0:256) Ps2 | [256:512) Pd2
           float* __restrict__ alsrcn, float* __restrict__ aldstn, int N_) {
  int t = threadIdx.x;
  int n0 = blockIdx.x * 4;
  int h = t >> 5, k = t & 31;
  __shared__ float den[4][NH];
  __shared__ float4 zs4[64];
  __shared__ float4 gs4[64];
  __shared__ float red[HC];
  __shared__ float xrow[FIN];
  float* zs = (float*)zs4;
  float* gs = (float*)gs4;

  // denominators: wave w handles node n0+w, shuffle-reduce mod 8
  {
    int w = t >> 6, lane = t & 63;
    int nn = n0 + w;
    if (nn < N_) {
      int f = rowptr[nn] * NH + lane, fe = rowptr[nn + 1] * NH;
      float dv = 0.f;
      for (; f < fe; f += 64) dv += ex_s[f];
      dv += __shfl_xor(dv, 8, 64);
      dv += __shfl_xor(dv, 16, 64);
      dv += __shfl_xor(dv, 32, 64);
      if (lane < NH) den[w][lane] = 1.0f / (dv + 1e-16f);
    }
  }
  __syncthreads();

  // phase 2: every thread FMAs every edge of its node (x gather = 64B/edge)
  float acc[4] = {0.f, 0.f, 0.f, 0.f};
#pragma unroll
  for (int i = 0; i < 4; ++i) {
    int nn = n0 + i;
    if (nn >= N_) continue;
    int j = rowptr[nn], je = rowptr[nn + 1];
    for (; j + 3 < je; j += 4) {
      int s0 = srcs[j], s1 = srcs[j + 1], s2 = srcs[j + 2], s3 = srcs[j + 3];
      float w0 = ex_s[j * NH + h];
      float w1 = ex_s[(j + 1) * NH + h];
      float w2 = ex_s[(j + 2) * NH + h];
      float w3 = ex_s[(j + 3) * NH + h];
      float x0 = __bfloat162float(xq[s0 * FIN + k]);
      float x1 = __bfloat162float(xq[s1 * FIN + k]);
      float x2 = __bfloat162float(xq[s2 * FIN + k]);
      float x3 = __bfloat162float(xq[s3 * FIN + k]);
      acc[i] = fmaf(x0, w0, acc[i]); acc[i] = fmaf(x1, w1, acc[i]);
      acc[i] = fmaf(x2, w2, acc[i]); acc[i] = fmaf(x3, w3, acc[i]);
    }
    for (; j < je; ++j) {
      int s0 = srcs[j];
      float w0 = ex_s[j * NH + h];
      float x0 = __bfloat162float(xq[s0 * FIN + k]);
      acc[i] = fmaf(x0, w0, acc[i]);
    }
  }

  // per-node epilogue: z -> g = relu(zW+b) -> lin -> (bf16 x' + next logits)
#pragma unroll
  for (int i = 0; i < 4; ++i) {
    int nn = n0 + i;
    bool act = (nn < N_);           // block-uniform
    if (act) zs[t] = acc[i] * den[i][h];
    __syncthreads();
    if (act) {
      float g = b[t];
#pragma unroll
      for (int k4 = 0; k4 < 8; ++k4) {
        float4 z4 = zs4[h * 8 + k4];
        g = fmaf(z4.x, W[(k4 * 4 + 0) * HC + t], g);
        g = fmaf(z4.y, W[(k4 * 4 + 1) * HC + t], g);
        g = fmaf(z4.z, W[(k4 * 4 + 2) * HC + t], g);
        g = fmaf(z4.w, W[(k4 * 4 + 3) * HC + t], g);
      }
      gs[t] = (g > 0.f) ? g : 0.f;
    }
    __syncthreads();
    if (act) {
      int kk = t & (K - 1), r = t >> LOG2K;
      float part = 0.f;
#pragma unroll
      for (int i4 = 0; i4 < K / 4; ++i4) {
        float4 g4 = gs4[r * (K / 4) + i4];
        int jj = r * K + i4 * 4;
        part = fmaf(g4.x, Wlin[(jj + 0) * K + kk], part);
        part = fmaf(g4.y, Wlin[(jj + 1) * K + kk], part);
        part = fmaf(g4.z, Wlin[(jj + 2) * K + kk], part);
        part = fmaf(g4.w, Wlin[(jj + 3) * K + kk], part);
      }
      red[t] = part;
    }
    __syncthreads();
    if (act && t < K) {
      float s = blin[t];
#pragma unroll
      for (int r2 = 0; r2 < HC / K; ++r2) s += red[r2 * K + t];
      if (LOGITS) { xrow[t] = s; xqn[(size_t)nn * FIN + t] = __float2bfloat16(s); }
      else        { xoutf[(size_t)nn * K + t] = s; }
    }
    if (LOGITS) {
      __syncthreads();
      if (act && t < NH) {
        float sa = 0.f, sd = 0.f;
#pragma unroll
        for (int k2 = 0; k2 < FIN; ++k2) {
          float x = xrow[k2];
          sa = fmaf(x, Pn[k2 * 8 + t], sa);
          sd = fmaf(x, Pn[256 + k2 * 8 + t], sd);
        }
        alsrcn[(size_t)nn * NH + t] = sa;
        aldstn[(size_t)nn * NH + t] = sd;
      }
    }
    __syncthreads();
  }
}

// ---------------- classifier: sigmoid(sum(fu*fm)) ----------------------------
__global__ void clf_kernel(const int* __restrict__ eli, const float* __restrict__ ela,
                           const float* __restrict__ x2, const float* __restrict__ clfW,
                           const float* __restrict__ clfb, float* __restrict__ out, int L_) {
  int i = blockIdx.x * blockDim.x + threadIdx.x;
  if (i >= L_) return;
  int u = eli[i], m = eli[L_ + i];
  const float4* xup = (const float4*)(x2 + (size_t)u * NH);
  const float4* xmp = (const float4*)(x2 + (size_t)m * NH);
  const float4* eap = (const float4*)(ela + (size_t)i * NH);
  float4 xu0 = xup[0], xu1 = xup[1];
  float4 xm0 = xmp[0], xm1 = xmp[1];
  float4 el0 = eap[0], el1 = eap[1];
  float xu[NH] = {xu0.x, xu0.y, xu0.z, xu0.w, xu1.x, xu1.y, xu1.z, xu1.w};
  float xm[NH] = {xm0.x, xm0.y, xm0.z, xm0.w, xm1.x, xm1.y, xm1.z, xm1.w};
  float el[NH] = {el0.x, el0.y, el0.z, el0.w, el1.x, el1.y, el1.z, el1.w};
  float fu[NH];
#pragma unroll
  for (int kk = 0; kk < NH; ++kk) fu[kk] = clfb[kk];
#pragma unroll
  for (int j = 0; j < NH; ++j) {
#pragma unroll
    for (int kk = 0; kk < NH; ++kk) fu[kk] = fmaf(xu[j], clfW[j * NH + kk], fu[kk]);
  }
#pragma unroll
  for (int j = 0; j < NH; ++j) {
#pragma unroll
    for (int kk = 0; kk < NH; ++kk) fu[kk] = fmaf(el[j], clfW[(NH + j) * NH + kk], fu[kk]);
  }
  float dot = 0.f;
#pragma unroll
  for (int kk = 0; kk < NH; ++kk) dot += fu[kk] * xm[kk];
  out[i] = 1.f / (1.f + expf(-dot));
}

extern "C" void kernel_launch(void* const* d_in, const int* in_sizes, int n_in,
                              void* d_out, int out_size, void* d_ws, size_t ws_size,
                              hipStream_t stream) {
  const int* node_ids   = (const int*)d_in[0];
  const int* edge_index = (const int*)d_in[1];
  const int* eli        = (const int*)d_in[2];
  const float* edge_attr = (const float*)d_in[4];
  const float* ela       = (const float*)d_in[5];
  const float* emb       = (const float*)d_in[6];
  const float* W1     = (const float*)d_in[7];
  const float* a_src1 = (const float*)d_in[8];
  const float* a_dst1 = (const float*)d_in[9];
  const float* We1    = (const float*)d_in[10];
  const float* a_e1   = (const float*)d_in[11];
  const float* b1     = (const float*)d_in[12];
  const float* lin1W  = (const float*)d_in[13];
  const float* lin1b  = (const float*)d_in[14];
  const float* W2     = (const float*)d_in[15];
  const float* a_src2 = (const float*)d_in[16];
  const float* a_dst2 = (const float*)d_in[17];
  const float* We2    = (const float*)d_in[18];
  const float* a_e2   = (const float*)d_in[19];
  const float* b2     = (const float*)d_in[20];
  const float* lin5W  = (const float*)d_in[21];
  const float* lin5b  = (const float*)d_in[22];
  const float* clfW   = (const float*)d_in[23];
  const float* clfb   = (const float*)d_in[24];

  const int N_ = in_sizes[0];
  const int E_ = in_sizes[1] / 2;
  const int L_ = in_sizes[2] / 2;
  const int* src  = edge_index;
  const int* dstp = edge_index + E_;

  char* p = (char*)d_ws;
  auto carve = [&](size_t bytes) -> char* {
    char* r = p;
    p += (bytes + 255) & ~(size_t)255;
    return r;
  };
  float* exbuf  = (float*)carve((size_t)E_ * NH * 4);   // 25.6 MB
  float* eal1   = (float*)carve((size_t)E_ * NH * 4);   // 25.6 MB
  float* eal2   = (float*)carve((size_t)E_ * NH * 4);   // 25.6 MB
  bf16*  xq1    = (bf16*)carve((size_t)N_ * FIN * 2);
  bf16*  xq2    = (bf16*)carve((size_t)N_ * FIN * 2);
  float* alsrc1 = (float*)carve((size_t)N_ * NH * 4);
  float* aldst1 = (float*)carve((size_t)N_ * NH * 4);
  float* alsrc2 = (float*)carve((size_t)N_ * NH * 4);
  float* aldst2 = (float*)carve((size_t)N_ * NH * 4);
  float* x2b    = (float*)carve((size_t)N_ * NH * 4);
  float* Mbuf   = (float*)carve(1152 * 4);
  int*   cnt    = (int*)carve((size_t)N_ * 4);
  int*   rowptr = (int*)carve((size_t)(N_ + 1) * 4);
  int*   fill   = (int*)carve((size_t)N_ * 4);
  int*   srcs   = (int*)carve((size_t)E_ * 4);
  int*   dsts   = (int*)carve((size_t)E_ * 4);

  hipMemsetAsync(cnt, 0, (size_t)N_ * 4, stream);
  int eb = (E_ + 255) / 256;
  fold_kernel<<<1, 256, 0, stream>>>(We1, a_e1, We2, a_e2, W1, a_src1, a_dst1,
                                     W2, a_src2, a_dst2, Mbuf);
  count_kernel<<<eb, 256, 0, stream>>>(dstp, cnt, E_);
  scan_kernel<<<1, 1024, 0, stream>>>(cnt, rowptr, fill, N_, E_);
  scatter_kernel<<<eb, 256, 0, stream>>>(src, dstp, fill, edge_attr, Mbuf,
                                         srcs, dsts, eal1, eal2, E_);
  prep1_kernel<<<(N_ + 7) / 8, 256, 0, stream>>>(emb, node_ids, Mbuf + 128,
                                                 xq1, alsrc1, aldst1, N_);

  // ---- layer 1 ----
  edge_kernel<<<eb, 256, 0, stream>>>(srcs, dsts, eal1, alsrc1, aldst1, exbuf, E_);
  agg_kernel<32, 5, true><<<(N_ + 3) / 4, 256, 0, stream>>>(
      rowptr, srcs, exbuf, xq1, W1, b1, lin1W, lin1b,
      nullptr, xq2, Mbuf + 640, alsrc2, aldst2, N_);

  // ---- layer 2 ----
  edge_kernel<<<eb, 256, 0, stream>>>(srcs, dsts, eal2, alsrc2, aldst2, exbuf, E_);
  agg_kernel<8, 3, false><<<(N_ + 3) / 4, 256, 0, stream>>>(
      rowptr, srcs, exbuf, xq2, W2, b2, lin5W, lin5b,
      x2b, nullptr, nullptr, nullptr, nullptr, N_);

  // ---- classifier ----
  clf_kernel<<<(L_ + 255) / 256, 256, 0, stream>>>(eli, ela, x2b, clfW, clfb,
                                                   (float*)d_out, L_);
}

// Round 8
// 572.094 us; speedup vs baseline: 1.3781x; 1.3781x over previous
//
#include <hip/hip_runtime.h>
#include <hip/hip_bf16.h>

#define HC    256
#define FIN   32
#define NH    8
#define GROUP 4     // dst nodes per block
#define CAP   128   // staged edges per chunk

typedef __hip_bfloat16 bf16;

__device__ __forceinline__ float blo(unsigned int u) { return __uint_as_float(u << 16); }
__device__ __forceinline__ float bhi(unsigned int u) { return __uint_as_float(u & 0xffff0000u); }

// ---------------- CSR build ---------------------------------------------------
__global__ void count_kernel(const int* __restrict__ dst, int* __restrict__ cnt, int E_) {
  int e = blockIdx.x * blockDim.x + threadIdx.x;
  if (e < E_) atomicAdd(&cnt[dst[e]], 1);
}

__global__ void scan_kernel(const int* __restrict__ cnt, int* __restrict__ rowptr,
                            int* __restrict__ fill, int N_, int E_) {
  __shared__ int part[1024];
  int t = threadIdx.x;
  int chunk = (N_ + 1023) / 1024;
  int lo = t * chunk, hi = lo + chunk;
  if (lo > N_) lo = N_;
  if (hi > N_) hi = N_;
  int s = 0;
  for (int i = lo; i < hi; ++i) s += cnt[i];
  part[t] = s;
  __syncthreads();
  for (int off = 1; off < 1024; off <<= 1) {
    int v = (t >= off) ? part[t - off] : 0;
    __syncthreads();
    part[t] += v;
    __syncthreads();
  }
  int run = part[t] - s;
  for (int i = lo; i < hi; ++i) { rowptr[i] = run; fill[i] = run; run += cnt[i]; }
  if (t == 0) rowptr[N_] = E_;
}

__global__ void scatter_kernel(const int* __restrict__ src, const int* __restrict__ dst,
                               int* __restrict__ fill, int* __restrict__ perm,
                               int* __restrict__ srcs, int E_) {
  int e = blockIdx.x * blockDim.x + threadIdx.x;
  if (e < E_) {
    int pos = atomicAdd(&fill[dst[e]], 1);
    perm[pos] = e;
    srcs[pos] = src[e];
  }
}

// ---- fold: M_l[8x8] = We_l x a_e_l ; P_ls/P_ld[32x8] = W_l x a_{src/dst}_l ----
// Mbuf floats: [0:64) M1 | [64:128) M2 | [128:384) P1s | [384:640) P1d
//              | [640:896) P2s | [896:1152) P2d
__global__ void fold_kernel(const float* __restrict__ We1, const float* __restrict__ ae1,
                            const float* __restrict__ We2, const float* __restrict__ ae2,
                            const float* __restrict__ W1, const float* __restrict__ as1,
                            const float* __restrict__ ad1,
                            const float* __restrict__ W2, const float* __restrict__ as2,
                            const float* __restrict__ ad2,
                            float* __restrict__ M) {
  for (int idx = threadIdx.x; idx < 1152; idx += 256) {
    const float* A; const float* V; int i;
    if (idx < 64)       { i = idx;       A = We1; V = ae1; }
    else if (idx < 128) { i = idx - 64;  A = We2; V = ae2; }
    else if (idx < 384) { i = idx - 128; A = W1;  V = as1; }
    else if (idx < 640) { i = idx - 384; A = W1;  V = ad1; }
    else if (idx < 896) { i = idx - 640; A = W2;  V = as2; }
    else                { i = idx - 896; A = W2;  V = ad2; }
    int k = i >> 3, h = i & 7;
    float s = 0.f;
    for (int c = 0; c < FIN; ++c)
      s = fmaf(A[k * HC + h * FIN + c], V[h * FIN + c], s);
    M[idx] = s;
  }
}

// ---- layer-1 prep: xq1 = bf16(emb[node_ids]); alsrc1/aldst1 = x @ P1 --------
__global__ __launch_bounds__(256) void
prep1_kernel(const float* __restrict__ emb, const int* __restrict__ node_ids,
             const float* __restrict__ P,
             bf16* __restrict__ xq, float* __restrict__ alsrc,
             float* __restrict__ aldst, int N_) {
  __shared__ float xs[8][33];
  int t = threadIdx.x, n0 = blockIdx.x * 8;
  int nl = t >> 5, c = t & 31;
  int n = n0 + nl;
  if (n < N_) {
    float v = emb[(size_t)node_ids[n] * FIN + c];
    xq[(size_t)n * FIN + c] = __float2bfloat16(v);
    xs[nl][c] = v;
  }
  __syncthreads();
  if (t < 64) {
    int nl2 = t >> 3, h = t & 7;
    int n2 = n0 + nl2;
    if (n2 < N_) {
      float sa = 0.f, sd = 0.f;
#pragma unroll
      for (int k = 0; k < FIN; ++k) {
        float x = xs[nl2][k];
        sa = fmaf(x, P[k * 8 + h], sa);
        sd = fmaf(x, P[256 + k * 8 + h], sd);
      }
      alsrc[(size_t)n2 * NH + h] = sa;
      aldst[(size_t)n2 * NH + h] = sd;
    }
  }
}

// ---- fused agg: stage x+ex in LDS once, FMA from LDS, batched epilogue ------
template <int K, int LOG2K, bool LOGITS>
__global__ __launch_bounds__(256) void
agg_kernel(const int* __restrict__ rowptr, const int* __restrict__ perm,
           const int* __restrict__ srcs,
           const float* __restrict__ edge_attr, const float* __restrict__ Mg,
           const float* __restrict__ alsrc, const float* __restrict__ aldst,
           const bf16* __restrict__ xq,
           const float* __restrict__ W, const float* __restrict__ b,
           const float* __restrict__ Wlin, const float* __restrict__ blin,
           float* __restrict__ xoutf, bf16* __restrict__ xqn,
           const float* __restrict__ Pn,
           float* __restrict__ alsrcn, float* __restrict__ aldstn, int N_) {
  __shared__ __align__(16) char smem[22016];
  float* xs     = (float*)smem;            // CAP*32 f = 16 KB; epilogue: zs|gs|red
  float* ws     = (float*)(smem + 16384);  // CAP*8 f = 4 KB;  epilogue: xrow
  int*   srcs_s = (int*)(smem + 20480);    // CAP
  int*   perm_s = (int*)(smem + 20992);    // CAP
  float* Ms     = (float*)(smem + 21504);  // 64
  float* ald_s  = (float*)(smem + 21760);  // GROUP*8
  float* den_s  = (float*)(smem + 21888);  // GROUP*8

  int t = threadIdx.x;
  int n0 = blockIdx.x * GROUP;
  int h = t >> 5, k = t & 31;

  int rp[GROUP + 1];
#pragma unroll
  for (int i = 0; i <= GROUP; ++i) {
    int nn = n0 + i;
    rp[i] = rowptr[(nn <= N_) ? nn : N_];
  }
  if (t < 64) Ms[t] = Mg[t];
  if (t < GROUP * NH) {
    int nn = n0 + (t >> 3);
    ald_s[t] = (nn < N_) ? aldst[(size_t)nn * NH + (t & 7)] : 0.f;
  }

  float acc[GROUP], deng[GROUP];
#pragma unroll
  for (int i = 0; i < GROUP; ++i) { acc[i] = 0.f; deng[i] = 0.f; }

  int beg = rp[0], end = rp[GROUP];
  for (int cbeg = beg; cbeg < end; cbeg += CAP) {
    int clen = end - cbeg; if (clen > CAP) clen = CAP;
    if (t < clen) { srcs_s[t] = srcs[cbeg + t]; perm_s[t] = perm[cbeg + t]; }
    __syncthreads();
    // stage x rows (bf16 -> f32), 8 lanes per edge, uint2 each
    int ntask = clen * 8;
    for (int idx = t; idx < ntask; idx += 256) {
      int e = idx >> 3, c4 = idx & 7;
      int s = srcs_s[e];
      uint2 v = *(const uint2*)(xq + (size_t)s * FIN + c4 * 4);
      float4 f = make_float4(blo(v.x), bhi(v.x), blo(v.y), bhi(v.y));
      *(float4*)&xs[e * 32 + c4 * 4] = f;
    }
    // stage ex: one thread per edge
    if (t < clen) {
      int j = cbeg + t;
      int ii = 0;
      while (j >= rp[ii + 1]) ++ii;     // node of this edge (<=3 iters)
      int e = perm_s[t], s = srcs_s[t];
      const float4* eap = (const float4*)(edge_attr + (size_t)e * NH);
      float4 ea0 = eap[0], ea1 = eap[1];
      float ea[NH] = {ea0.x, ea0.y, ea0.z, ea0.w, ea1.x, ea1.y, ea1.z, ea1.w};
      const float4* asp = (const float4*)(alsrc + (size_t)s * NH);
      float4 as0 = asp[0], as1 = asp[1];
      float als[NH] = {as0.x, as0.y, as0.z, as0.w, as1.x, as1.y, as1.z, as1.w};
      float o[NH];
#pragma unroll
      for (int hh = 0; hh < NH; ++hh) {
        float al = 0.f;
#pragma unroll
        for (int kk = 0; kk < NH; ++kk) al = fmaf(ea[kk], Ms[kk * NH + hh], al);
        float a = als[hh] + ald_s[ii * NH + hh] + al;
        a = (a >= 0.f) ? a : 0.2f * a;
        o[hh] = __expf(a);
      }
      *(float4*)&ws[t * 8]     = make_float4(o[0], o[1], o[2], o[3]);
      *(float4*)&ws[t * 8 + 4] = make_float4(o[4], o[5], o[6], o[7]);
    }
    __syncthreads();
    // FMA from LDS: w broadcast, x conflict-free
#pragma unroll
    for (int i = 0; i < GROUP; ++i) {
      int lo = rp[i] > cbeg ? rp[i] - cbeg : 0;
      int hi = rp[i + 1] - cbeg; if (hi > clen) hi = clen;
      float a = acc[i], dn = deng[i];
      for (int le = lo; le < hi; ++le) {
        float w = ws[le * 8 + h];
        float x = xs[le * 32 + k];
        a = fmaf(x, w, a);
        dn += (k == 0) ? w : 0.f;
      }
      acc[i] = a; deng[i] = dn;
    }
    __syncthreads();
  }

  if (k == 0) {
#pragma unroll
    for (int i = 0; i < GROUP; ++i) den_s[i * 8 + h] = deng[i];
  }
  __syncthreads();

  float* zs  = xs;          // GROUP*256
  float* gs  = xs + 1024;   // GROUP*256
  float* red = xs + 2048;   // GROUP*256
#pragma unroll
  for (int i = 0; i < GROUP; ++i) {
    float rden = 1.0f / (den_s[i * 8 + h] + 1e-16f);
    zs[i * 256 + t] = acc[i] * rden;
  }
  __syncthreads();

  // g = relu(z @ W + b): W column loaded once, reused x GROUP
  float g[GROUP];
#pragma unroll
  for (int i = 0; i < GROUP; ++i) g[i] = b[t];
#pragma unroll
  for (int k4 = 0; k4 < 8; ++k4) {
    float za[GROUP][4];
#pragma unroll
    for (int i = 0; i < GROUP; ++i)
      *(float4*)za[i] = *(const float4*)&zs[i * 256 + h * 32 + k4 * 4];
#pragma unroll
    for (int kk = 0; kk < 4; ++kk) {
      float wv = W[(k4 * 4 + kk) * HC + t];
#pragma unroll
      for (int i = 0; i < GROUP; ++i) g[i] = fmaf(za[i][kk], wv, g[i]);
    }
  }
#pragma unroll
  for (int i = 0; i < GROUP; ++i) gs[i * 256 + t] = (g[i] > 0.f) ? g[i] : 0.f;
  __syncthreads();

  // lin: xout = g @ Wlin + blin (Wlin element reused x GROUP)
  {
    int kk = t & (K - 1), r = t >> LOG2K;
    float part[GROUP];
#pragma unroll
    for (int i = 0; i < GROUP; ++i) part[i] = 0.f;
#pragma unroll
    for (int j4 = 0; j4 < K / 4; ++j4) {
      float ga[GROUP][4];
#pragma unroll
      for (int i = 0; i < GROUP; ++i)
        *(float4*)ga[i] = *(const float4*)&gs[i * 256 + r * K + j4 * 4];
#pragma unroll
      for (int jj = 0; jj < 4; ++jj) {
        float wl = Wlin[(r * K + j4 * 4 + jj) * K + kk];
#pragma unroll
        for (int i = 0; i < GROUP; ++i) part[i] = fmaf(ga[i][jj], wl, part[i]);
      }
    }
#pragma unroll
    for (int i = 0; i < GROUP; ++i) red[i * 256 + t] = part[i];
  }
  __syncthreads();

  if (LOGITS) {
    float* xrow = ws;                  // GROUP*32
    if (t < GROUP * 32) {
      int i = t >> 5, kk = t & 31;
      float s = blin[kk];
#pragma unroll
      for (int r2 = 0; r2 < HC / K; ++r2) s += red[i * 256 + r2 * K + kk];
      int nn = n0 + i;
      if (nn < N_) xqn[(size_t)nn * FIN + kk] = __float2bfloat16(s);
      xrow[t] = s;
    }
    __syncthreads();
    if (t < GROUP * NH) {
      int i = t >> 3, hh = t & 7;
      int nn = n0 + i;
      if (nn < N_) {
        float sa = 0.f, sd = 0.f;
#pragma unroll
        for (int k2 = 0; k2 < FIN; ++k2) {
          float x = xrow[i * 32 + k2];
          sa = fmaf(x, Pn[k2 * 8 + hh], sa);
          sd = fmaf(x, Pn[256 + k2 * 8 + hh], sd);
        }
        alsrcn[(size_t)nn * NH + hh] = sa;
        aldstn[(size_t)nn * NH + hh] = sd;
      }
    }
  } else {
    if (t < GROUP * K) {
      int i = t >> LOG2K, kk = t & (K - 1);
      float s = blin[kk];
#pragma unroll
      for (int r2 = 0; r2 < HC / K; ++r2) s += red[i * 256 + r2 * K + kk];
      int nn = n0 + i;
      if (nn < N_) xoutf[(size_t)nn * K + kk] = s;
    }
  }
}

// ---------------- classifier: sigmoid(sum(fu*fm)) ----------------------------
__global__ void clf_kernel(const int* __restrict__ eli, const float* __restrict__ ela,
                           const float* __restrict__ x2, const float* __restrict__ clfW,
                           const float* __restrict__ clfb, float* __restrict__ out, int L_) {
  int i = blockIdx.x * blockDim.x + threadIdx.x;
  if (i >= L_) return;
  int u = eli[i], m = eli[L_ + i];
  const float4* xup = (const float4*)(x2 + (size_t)u * NH);
  const float4* xmp = (const float4*)(x2 + (size_t)m * NH);
  const float4* eap = (const float4*)(ela + (size_t)i * NH);
  float4 xu0 = xup[0], xu1 = xup[1];
  float4 xm0 = xmp[0], xm1 = xmp[1];
  float4 el0 = eap[0], el1 = eap[1];
  float xu[NH] = {xu0.x, xu0.y, xu0.z, xu0.w, xu1.x, xu1.y, xu1.z, xu1.w};
  float xm[NH] = {xm0.x, xm0.y, xm0.z, xm0.w, xm1.x, xm1.y, xm1.z, xm1.w};
  float el[NH] = {el0.x, el0.y, el0.z, el0.w, el1.x, el1.y, el1.z, el1.w};
  float fu[NH];
#pragma unroll
  for (int kk = 0; kk < NH; ++kk) fu[kk] = clfb[kk];
#pragma unroll
  for (int j = 0; j < NH; ++j) {
#pragma unroll
    for (int kk = 0; kk < NH; ++kk) fu[kk] = fmaf(xu[j], clfW[j * NH + kk], fu[kk]);
  }
#pragma unroll
  for (int j = 0; j < NH; ++j) {
#pragma unroll
    for (int kk = 0; kk < NH; ++kk) fu[kk] = fmaf(el[j], clfW[(NH + j) * NH + kk], fu[kk]);
  }
  float dot = 0.f;
#pragma unroll
  for (int kk = 0; kk < NH; ++kk) dot += fu[kk] * xm[kk];
  out[i] = 1.f / (1.f + expf(-dot));
}

extern "C" void kernel_launch(void* const* d_in, const int* in_sizes, int n_in,
                              void* d_out, int out_size, void* d_ws, size_t ws_size,
                              hipStream_t stream) {
  const int* node_ids   = (const int*)d_in[0];
  const int* edge_index = (const int*)d_in[1];
  const int* eli        = (const int*)d_in[2];
  const float* edge_attr = (const float*)d_in[4];
  const float* ela       = (const float*)d_in[5];
  const float* emb       = (const float*)d_in[6];
  const float* W1     = (const float*)d_in[7];
  const float* a_src1 = (const float*)d_in[8];
  const float* a_dst1 = (const float*)d_in[9];
  const float* We1    = (const float*)d_in[10];
  const float* a_e1   = (const float*)d_in[11];
  const float* b1     = (const float*)d_in[12];
  const float* lin1W  = (const float*)d_in[13];
  const float* lin1b  = (const float*)d_in[14];
  const float* W2     = (const float*)d_in[15];
  const float* a_src2 = (const float*)d_in[16];
  const float* a_dst2 = (const float*)d_in[17];
  const float* We2    = (const float*)d_in[18];
  const float* a_e2   = (const float*)d_in[19];
  const float* b2     = (const float*)d_in[20];
  const float* lin5W  = (const float*)d_in[21];
  const float* lin5b  = (const float*)d_in[22];
  const float* clfW   = (const float*)d_in[23];
  const float* clfb   = (const float*)d_in[24];

  const int N_ = in_sizes[0];
  const int E_ = in_sizes[1] / 2;
  const int L_ = in_sizes[2] / 2;
  const int* src  = edge_index;
  const int* dstp = edge_index + E_;

  char* p = (char*)d_ws;
  auto carve = [&](size_t bytes) -> char* {
    char* r = p;
    p += (bytes + 255) & ~(size_t)255;
    return r;
  };
  bf16*  xq1    = (bf16*)carve((size_t)N_ * FIN * 2);
  bf16*  xq2    = (bf16*)carve((size_t)N_ * FIN * 2);
  float* alsrc1 = (float*)carve((size_t)N_ * NH * 4);
  float* aldst1 = (float*)carve((size_t)N_ * NH * 4);
  float* alsrc2 = (float*)carve((size_t)N_ * NH * 4);
  float* aldst2 = (float*)carve((size_t)N_ * NH * 4);
  float* x2b    = (float*)carve((size_t)N_ * NH * 4);
  float* Mbuf   = (float*)carve(1152 * 4);
  int*   cnt    = (int*)carve((size_t)N_ * 4);
  int*   rowptr = (int*)carve((size_t)(N_ + 1) * 4);
  int*   fill   = (int*)carve((size_t)N_ * 4);
  int*   perm   = (int*)carve((size_t)E_ * 4);
  int*   srcs   = (int*)carve((size_t)E_ * 4);

  hipMemsetAsync(cnt, 0, (size_t)N_ * 4, stream);
  int eb = (E_ + 255) / 256;
  fold_kernel<<<1, 256, 0, stream>>>(We1, a_e1, We2, a_e2, W1, a_src1, a_dst1,
                                     W2, a_src2, a_dst2, Mbuf);
  count_kernel<<<eb, 256, 0, stream>>>(dstp, cnt, E_);
  scan_kernel<<<1, 1024, 0, stream>>>(cnt, rowptr, fill, N_, E_);
  scatter_kernel<<<eb, 256, 0, stream>>>(src, dstp, fill, perm, srcs, E_);
  prep1_kernel<<<(N_ + 7) / 8, 256, 0, stream>>>(emb, node_ids, Mbuf + 128,
                                                 xq1, alsrc1, aldst1, N_);

  int gb = (N_ + GROUP - 1) / GROUP;
  // ---- layer 1 (fully fused: ex + softmax + agg + zW + lin1 + next logits) --
  agg_kernel<32, 5, true><<<gb, 256, 0, stream>>>(
      rowptr, perm, srcs, edge_attr, Mbuf, alsrc1, aldst1, xq1,
      W1, b1, lin1W, lin1b, nullptr, xq2, Mbuf + 640, alsrc2, aldst2, N_);

  // ---- layer 2 ----
  agg_kernel<8, 3, false><<<gb, 256, 0, stream>>>(
      rowptr, perm, srcs, edge_attr, Mbuf + 64, alsrc2, aldst2, xq2,
      W2, b2, lin5W, lin5b, x2b, nullptr, nullptr, nullptr, nullptr, N_);

  // ---- classifier ----
  clf_kernel<<<(L_ + 255) / 256, 256, 0, stream>>>(eli, ela, x2b, clfW, clfb,
                                                   (float*)d_out, L_);
}

// Round 9
// 534.548 us; speedup vs baseline: 1.4749x; 1.0702x over previous
//
#include <hip/hip_runtime.h>
#include <hip/hip_bf16.h>

#define HC    256
#define FIN   32
#define NH    8
#define GROUP 4     // dst nodes per block
#define CAP   128   // staged edges per chunk

typedef __hip_bfloat16 bf16;

__device__ __forceinline__ float blo(unsigned int u) { return __uint_as_float(u << 16); }
__device__ __forceinline__ float bhi(unsigned int u) { return __uint_as_float(u & 0xffff0000u); }

// ---------------- CSR build ---------------------------------------------------
__global__ void count_kernel(const int* __restrict__ dst, int* __restrict__ cnt, int E_) {
  int e = blockIdx.x * blockDim.x + threadIdx.x;
  if (e < E_) atomicAdd(&cnt[dst[e]], 1);
}

__global__ void scan_kernel(const int* __restrict__ cnt, int* __restrict__ rowptr,
                            int* __restrict__ fill, int N_, int E_) {
  __shared__ int part[1024];
  int t = threadIdx.x;
  int chunk = (N_ + 1023) / 1024;
  int lo = t * chunk, hi = lo + chunk;
  if (lo > N_) lo = N_;
  if (hi > N_) hi = N_;
  int s = 0;
  for (int i = lo; i < hi; ++i) s += cnt[i];
  part[t] = s;
  __syncthreads();
  for (int off = 1; off < 1024; off <<= 1) {
    int v = (t >= off) ? part[t - off] : 0;
    __syncthreads();
    part[t] += v;
    __syncthreads();
  }
  int run = part[t] - s;
  for (int i = lo; i < hi; ++i) { rowptr[i] = run; fill[i] = run; run += cnt[i]; }
  if (t == 0) rowptr[N_] = E_;
}

__global__ void scatter_kernel(const int* __restrict__ src, const int* __restrict__ dst,
                               int* __restrict__ fill, int* __restrict__ perm,
                               int* __restrict__ srcs, int E_) {
  int e = blockIdx.x * blockDim.x + threadIdx.x;
  if (e < E_) {
    int pos = atomicAdd(&fill[dst[e]], 1);
    perm[pos] = e;
    srcs[pos] = src[e];
  }
}

// ---- fold: M_l[8x8] = We_l x a_e_l ; P_ls/P_ld[32x8] = W_l x a_{src/dst}_l ----
// Mbuf floats: [0:64) M1 | [64:128) M2 | [128:384) P1s | [384:640) P1d
//              | [640:896) P2s | [896:1152) P2d
__global__ void fold_kernel(const float* __restrict__ We1, const float* __restrict__ ae1,
                            const float* __restrict__ We2, const float* __restrict__ ae2,
                            const float* __restrict__ W1, const float* __restrict__ as1,
                            const float* __restrict__ ad1,
                            const float* __restrict__ W2, const float* __restrict__ as2,
                            const float* __restrict__ ad2,
                            float* __restrict__ M) {
  for (int idx = threadIdx.x; idx < 1152; idx += 256) {
    const float* A; const float* V; int i;
    if (idx < 64)       { i = idx;       A = We1; V = ae1; }
    else if (idx < 128) { i = idx - 64;  A = We2; V = ae2; }
    else if (idx < 384) { i = idx - 128; A = W1;  V = as1; }
    else if (idx < 640) { i = idx - 384; A = W1;  V = ad1; }
    else if (idx < 896) { i = idx - 640; A = W2;  V = as2; }
    else                { i = idx - 896; A = W2;  V = ad2; }
    int k = i >> 3, h = i & 7;
    float s = 0.f;
    for (int c = 0; c < FIN; ++c)
      s = fmaf(A[k * HC + h * FIN + c], V[h * FIN + c], s);
    M[idx] = s;
  }
}

// ---- layer-1 prep: xq1 = bf16(emb[node_ids]); alsrc1/aldst1 = x @ P1 --------
__global__ __launch_bounds__(256) void
prep1_kernel(const float* __restrict__ emb, const int* __restrict__ node_ids,
             const float* __restrict__ P,
             bf16* __restrict__ xq, float* __restrict__ alsrc,
             float* __restrict__ aldst, int N_) {
  __shared__ float xs[8][33];
  int t = threadIdx.x, n0 = blockIdx.x * 8;
  int nl = t >> 5, c = t & 31;
  int n = n0 + nl;
  if (n < N_) {
    float v = emb[(size_t)node_ids[n] * FIN + c];
    xq[(size_t)n * FIN + c] = __float2bfloat16(v);
    xs[nl][c] = v;
  }
  __syncthreads();
  if (t < 64) {
    int nl2 = t >> 3, h = t & 7;
    int n2 = n0 + nl2;
    if (n2 < N_) {
      float sa = 0.f, sd = 0.f;
#pragma unroll
      for (int k = 0; k < FIN; ++k) {
        float x = xs[nl2][k];
        sa = fmaf(x, P[k * 8 + h], sa);
        sd = fmaf(x, P[256 + k * 8 + h], sd);
      }
      alsrc[(size_t)n2 * NH + h] = sa;
      aldst[(size_t)n2 * NH + h] = sd;
    }
  }
}

// ---- fused agg: stage packed-x + ex in LDS, FMA from LDS, batched epilogue --
template <int K, int LOG2K, bool LOGITS>
__global__ __launch_bounds__(256) void
agg_kernel(const int* __restrict__ rowptr, const int* __restrict__ perm,
           const int* __restrict__ srcs,
           const float* __restrict__ edge_attr, const float* __restrict__ Mg,
           const float* __restrict__ alsrc, const float* __restrict__ aldst,
           const bf16* __restrict__ xq,
           const float* __restrict__ W, const float* __restrict__ b,
           const float* __restrict__ Wlin, const float* __restrict__ blin,
           float* __restrict__ xoutf, bf16* __restrict__ xqn,
           const float* __restrict__ Pn,
           float* __restrict__ alsrcn, float* __restrict__ aldstn, int N_) {
  __shared__ __align__(16) char smem[13568];
  unsigned int* xsu = (unsigned int*)smem;   // CAP*16 uints = 8 KB (2 bf16/word)
  float* wsf   = (float*)(smem + 8192);      // [NH][CAP] = 4 KB, conflict-free
  float* Ms    = (float*)(smem + 12288);     // 64
  float* ald_s = (float*)(smem + 12544);     // GROUP*8
  float* den_s = (float*)(smem + 12672);     // GROUP*8
  float* xrow  = (float*)(smem + 12800);     // GROUP*32 (LOGITS epilogue)

  int t = threadIdx.x;
  int n0 = blockIdx.x * GROUP;
  int h = t >> 5, k = t & 31;
  unsigned int msk = (k & 1) ? 0u : 1u;      // 1 => low half

  int rp[GROUP + 1];
#pragma unroll
  for (int i = 0; i <= GROUP; ++i) {
    int nn = n0 + i;
    rp[i] = rowptr[(nn <= N_) ? nn : N_];
  }
  if (t < 64) Ms[t] = Mg[t];
  if (t < GROUP * NH) {
    int nn = n0 + (t >> 3);
    ald_s[t] = (nn < N_) ? aldst[(size_t)nn * NH + (t & 7)] : 0.f;
  }
  __syncthreads();

  float acc[GROUP], deng[GROUP];
#pragma unroll
  for (int i = 0; i < GROUP; ++i) { acc[i] = 0.f; deng[i] = 0.f; }

  int beg = rp[0], end = rp[GROUP];
  for (int cbeg = beg; cbeg < end; cbeg += CAP) {
    int clen = end - cbeg; if (clen > CAP) clen = CAP;

    // stage x rows packed (8 lanes/edge, uint2 = 4 channels each)
    int ntask = clen * 8;
    for (int idx = t; idx < ntask; idx += 256) {
      int e = idx >> 3, c4 = idx & 7;
      int s = srcs[cbeg + e];
      uint2 v = *(const uint2*)(xq + (size_t)s * FIN + c4 * 4);
      xsu[e * 16 + c4 * 2]     = v.x;
      xsu[e * 16 + c4 * 2 + 1] = v.y;
    }
    // stage ex: 2 threads per edge, 4 heads each, halves swapped via shfl
    {
      int e2 = t >> 1, half = t & 1;
      if (e2 < clen) {
        int j = cbeg + e2;
        int ep = perm[j];
        int sn = srcs[j];
        int ii = 0;
        while (j >= rp[ii + 1]) ++ii;
        float4 eah = *(const float4*)(edge_attr + (size_t)ep * NH + half * 4);
        float4 ash = *(const float4*)(alsrc + (size_t)sn * NH + half * 4);
        float eaf[4] = {eah.x, eah.y, eah.z, eah.w};
        float ea[8];
#pragma unroll
        for (int c = 0; c < 4; ++c) {
          float other = __shfl_xor(eaf[c], 1, 64);
          ea[half * 4 + c] = eaf[c];
          ea[(1 - half) * 4 + c] = other;
        }
        float asf[4] = {ash.x, ash.y, ash.z, ash.w};
#pragma unroll
        for (int i = 0; i < 4; ++i) {
          int hh = half * 4 + i;
          float al = 0.f;
#pragma unroll
          for (int kk = 0; kk < NH; ++kk) al = fmaf(ea[kk], Ms[kk * NH + hh], al);
          float a = asf[i] + ald_s[ii * NH + hh] + al;
          a = (a >= 0.f) ? a : 0.2f * a;
          wsf[hh * CAP + e2] = __expf(a);
        }
      }
    }
    __syncthreads();
    // FMA from LDS: w broadcast, packed x broadcast-pair reads
#pragma unroll
    for (int i = 0; i < GROUP; ++i) {
      int lo = rp[i] > cbeg ? rp[i] - cbeg : 0;
      int hi = rp[i + 1] - cbeg; if (hi > clen) hi = clen;
      float a = acc[i], dn = deng[i];
#pragma unroll 4
      for (int le = lo; le < hi; ++le) {
        float w = wsf[h * CAP + le];
        unsigned int u = xsu[le * 16 + (k >> 1)];
        float x = __uint_as_float(msk ? (u << 16) : (u & 0xffff0000u));
        a = fmaf(x, w, a);
        dn += (k == 0) ? w : 0.f;
      }
      acc[i] = a; deng[i] = dn;
    }
    __syncthreads();
  }

  if (k == 0) {
#pragma unroll
    for (int i = 0; i < GROUP; ++i) den_s[i * 8 + h] = deng[i];
  }
  __syncthreads();

  float* zs  = (float*)smem;           // GROUP*256
  float* gs  = zs + 1024;              // GROUP*256
  float* red = zs + 2048;              // GROUP*256 (ends at 12288)
#pragma unroll
  for (int i = 0; i < GROUP; ++i) {
    float rden = 1.0f / (den_s[i * 8 + h] + 1e-16f);
    zs[i * 256 + t] = acc[i] * rden;
  }
  __syncthreads();

  // g = relu(z @ W + b): W column loaded once, reused x GROUP
  float g[GROUP];
#pragma unroll
  for (int i = 0; i < GROUP; ++i) g[i] = b[t];
#pragma unroll
  for (int k4 = 0; k4 < 8; ++k4) {
    float za[GROUP][4];
#pragma unroll
    for (int i = 0; i < GROUP; ++i)
      *(float4*)za[i] = *(const float4*)&zs[i * 256 + h * 32 + k4 * 4];
#pragma unroll
    for (int kk = 0; kk < 4; ++kk) {
      float wv = W[(k4 * 4 + kk) * HC + t];
#pragma unroll
      for (int i = 0; i < GROUP; ++i) g[i] = fmaf(za[i][kk], wv, g[i]);
    }
  }
  __syncthreads();
#pragma unroll
  for (int i = 0; i < GROUP; ++i) gs[i * 256 + t] = (g[i] > 0.f) ? g[i] : 0.f;
  __syncthreads();

  // lin: xout = g @ Wlin + blin (Wlin element reused x GROUP)
  {
    int kk = t & (K - 1), r = t >> LOG2K;
    float part[GROUP];
#pragma unroll
    for (int i = 0; i < GROUP; ++i) part[i] = 0.f;
#pragma unroll
    for (int j4 = 0; j4 < K / 4; ++j4) {
      float ga[GROUP][4];
#pragma unroll
      for (int i = 0; i < GROUP; ++i)
        *(float4*)ga[i] = *(const float4*)&gs[i * 256 + r * K + j4 * 4];
#pragma unroll
      for (int jj = 0; jj < 4; ++jj) {
        float wl = Wlin[(r * K + j4 * 4 + jj) * K + kk];
#pragma unroll
        for (int i = 0; i < GROUP; ++i) part[i] = fmaf(ga[i][jj], wl, part[i]);
      }
    }
    __syncthreads();
#pragma unroll
    for (int i = 0; i < GROUP; ++i) red[i * 256 + t] = part[i];
  }
  __syncthreads();

  if (LOGITS) {
    if (t < GROUP * 32) {
      int i = t >> 5, kk = t & 31;
      float s = blin[kk];
#pragma unroll
      for (int r2 = 0; r2 < HC / K; ++r2) s += red[i * 256 + r2 * K + kk];
      int nn = n0 + i;
      if (nn < N_) xqn[(size_t)nn * FIN + kk] = __float2bfloat16(s);
      xrow[t] = s;
    }
    __syncthreads();
    if (t < GROUP * NH) {
      int i = t >> 3, hh = t & 7;
      int nn = n0 + i;
      if (nn < N_) {
        float sa = 0.f, sd = 0.f;
#pragma unroll
        for (int k2 = 0; k2 < FIN; ++k2) {
          float x = xrow[i * 32 + k2];
          sa = fmaf(x, Pn[k2 * 8 + hh], sa);
          sd = fmaf(x, Pn[256 + k2 * 8 + hh], sd);
        }
        alsrcn[(size_t)nn * NH + hh] = sa;
        aldstn[(size_t)nn * NH + hh] = sd;
      }
    }
  } else {
    if (t < GROUP * K) {
      int i = t >> LOG2K, kk = t & (K - 1);
      float s = blin[kk];
#pragma unroll
      for (int r2 = 0; r2 < HC / K; ++r2) s += red[i * 256 + r2 * K + kk];
      int nn = n0 + i;
      if (nn < N_) xoutf[(size_t)nn * K + kk] = s;
    }
  }
}

// ---------------- classifier: sigmoid(sum(fu*fm)) ----------------------------
__global__ void clf_kernel(const int* __restrict__ eli, const float* __restrict__ ela,
                           const float* __restrict__ x2, const float* __restrict__ clfW,
                           const float* __restrict__ clfb, float* __restrict__ out, int L_) {
  int i = blockIdx.x * blockDim.x + threadIdx.x;
  if (i >= L_) return;
  int u = eli[i], m = eli[L_ + i];
  const float4* xup = (const float4*)(x2 + (size_t)u * NH);
  const float4* xmp = (const float4*)(x2 + (size_t)m * NH);
  const float4* eap = (const float4*)(ela + (size_t)i * NH);
  float4 xu0 = xup[0], xu1 = xup[1];
  float4 xm0 = xmp[0], xm1 = xmp[1];
  float4 el0 = eap[0], el1 = eap[1];
  float xu[NH] = {xu0.x, xu0.y, xu0.z, xu0.w, xu1.x, xu1.y, xu1.z, xu1.w};
  float xm[NH] = {xm0.x, xm0.y, xm0.z, xm0.w, xm1.x, xm1.y, xm1.z, xm1.w};
  float el[NH] = {el0.x, el0.y, el0.z, el0.w, el1.x, el1.y, el1.z, el1.w};
  float fu[NH];
#pragma unroll
  for (int kk = 0; kk < NH; ++kk) fu[kk] = clfb[kk];
#pragma unroll
  for (int j = 0; j < NH; ++j) {
#pragma unroll
    for (int kk = 0; kk < NH; ++kk) fu[kk] = fmaf(xu[j], clfW[j * NH + kk], fu[kk]);
  }
#pragma unroll
  for (int j = 0; j < NH; ++j) {
#pragma unroll
    for (int kk = 0; kk < NH; ++kk) fu[kk] = fmaf(el[j], clfW[(NH + j) * NH + kk], fu[kk]);
  }
  float dot = 0.f;
#pragma unroll
  for (int kk = 0; kk < NH; ++kk) dot += fu[kk] * xm[kk];
  out[i] = 1.f / (1.f + expf(-dot));
}

extern "C" void kernel_launch(void* const* d_in, const int* in_sizes, int n_in,
                              void* d_out, int out_size, void* d_ws, size_t ws_size,
                              hipStream_t stream) {
  const int* node_ids   = (const int*)d_in[0];
  const int* edge_index = (const int*)d_in[1];
  const int* eli        = (const int*)d_in[2];
  const float* edge_attr = (const float*)d_in[4];
  const float* ela       = (const float*)d_in[5];
  const float* emb       = (const float*)d_in[6];
  const float* W1     = (const float*)d_in[7];
  const float* a_src1 = (const float*)d_in[8];
  const float* a_dst1 = (const float*)d_in[9];
  const float* We1    = (const float*)d_in[10];
  const float* a_e1   = (const float*)d_in[11];
  const float* b1     = (const float*)d_in[12];
  const float* lin1W  = (const float*)d_in[13];
  const float* lin1b  = (const float*)d_in[14];
  const float* W2     = (const float*)d_in[15];
  const float* a_src2 = (const float*)d_in[16];
  const float* a_dst2 = (const float*)d_in[17];
  const float* We2    = (const float*)d_in[18];
  const float* a_e2   = (const float*)d_in[19];
  const float* b2     = (const float*)d_in[20];
  const float* lin5W  = (const float*)d_in[21];
  const float* lin5b  = (const float*)d_in[22];
  const float* clfW   = (const float*)d_in[23];
  const float* clfb   = (const float*)d_in[24];

  const int N_ = in_sizes[0];
  const int E_ = in_sizes[1] / 2;
  const int L_ = in_sizes[2] / 2;
  const int* src  = edge_index;
  const int* dstp = edge_index + E_;

  char* p = (char*)d_ws;
  auto carve = [&](size_t bytes) -> char* {
    char* r = p;
    p += (bytes + 255) & ~(size_t)255;
    return r;
  };
  bf16*  xq1    = (bf16*)carve((size_t)N_ * FIN * 2);
  bf16*  xq2    = (bf16*)carve((size_t)N_ * FIN * 2);
  float* alsrc1 = (float*)carve((size_t)N_ * NH * 4);
  float* aldst1 = (float*)carve((size_t)N_ * NH * 4);
  float* alsrc2 = (float*)carve((size_t)N_ * NH * 4);
  float* aldst2 = (float*)carve((size_t)N_ * NH * 4);
  float* x2b    = (float*)carve((size_t)N_ * NH * 4);
  float* Mbuf   = (float*)carve(1152 * 4);
  int*   cnt    = (int*)carve((size_t)N_ * 4);
  int*   rowptr = (int*)carve((size_t)(N_ + 1) * 4);
  int*   fill   = (int*)carve((size_t)N_ * 4);
  int*   perm   = (int*)carve((size_t)E_ * 4);
  int*   srcs   = (int*)carve((size_t)E_ * 4);

  hipMemsetAsync(cnt, 0, (size_t)N_ * 4, stream);
  int eb = (E_ + 255) / 256;
  fold_kernel<<<1, 256, 0, stream>>>(We1, a_e1, We2, a_e2, W1, a_src1, a_dst1,
                                     W2, a_src2, a_dst2, Mbuf);
  count_kernel<<<eb, 256, 0, stream>>>(dstp, cnt, E_);
  scan_kernel<<<1, 1024, 0, stream>>>(cnt, rowptr, fill, N_, E_);
  scatter_kernel<<<eb, 256, 0, stream>>>(src, dstp, fill, perm, srcs, E_);
  prep1_kernel<<<(N_ + 7) / 8, 256, 0, stream>>>(emb, node_ids, Mbuf + 128,
                                                 xq1, alsrc1, aldst1, N_);

  int gb = (N_ + GROUP - 1) / GROUP;
  // ---- layer 1 (fully fused: ex + softmax + agg + zW + lin1 + next logits) --
  agg_kernel<32, 5, true><<<gb, 256, 0, stream>>>(
      rowptr, perm, srcs, edge_attr, Mbuf, alsrc1, aldst1, xq1,
      W1, b1, lin1W, lin1b, nullptr, xq2, Mbuf + 640, alsrc2, aldst2, N_);

  // ---- layer 2 ----
  agg_kernel<8, 3, false><<<gb, 256, 0, stream>>>(
      rowptr, perm, srcs, edge_attr, Mbuf + 64, alsrc2, aldst2, xq2,
      W2, b2, lin5W, lin5b, x2b, nullptr, nullptr, nullptr, nullptr, N_);

  // ---- classifier ----
  clf_kernel<<<(L_ + 255) / 256, 256, 0, stream>>>(eli, ela, x2b, clfW, clfb,
                                                   (float*)d_out, L_);
}

// Round 10
// 501.389 us; speedup vs baseline: 1.5725x; 1.0661x over previous
//
#include <hip/hip_runtime.h>
#include <hip/hip_bf16.h>

#define HC    256
#define FIN   32
#define NH    8
#define GROUP 4     // dst nodes per block
#define CAP   128   // staged edges per chunk

typedef __hip_bfloat16 bf16;

__device__ __forceinline__ float blo(unsigned int u) { return __uint_as_float(u << 16); }
__device__ __forceinline__ float bhi(unsigned int u) { return __uint_as_float(u & 0xffff0000u); }

// ---------------- CSR build ---------------------------------------------------
__global__ void count_kernel(const int* __restrict__ dst, int* __restrict__ cnt, int E_) {
  int e = blockIdx.x * blockDim.x + threadIdx.x;
  if (e < E_) atomicAdd(&cnt[dst[e]], 1);
}

__global__ void scan_kernel(const int* __restrict__ cnt, int* __restrict__ rowptr,
                            int* __restrict__ fill, int N_, int E_) {
  __shared__ int part[1024];
  int t = threadIdx.x;
  int chunk = (N_ + 1023) / 1024;
  int lo = t * chunk, hi = lo + chunk;
  if (lo > N_) lo = N_;
  if (hi > N_) hi = N_;
  int s = 0;
  for (int i = lo; i < hi; ++i) s += cnt[i];
  part[t] = s;
  __syncthreads();
  for (int off = 1; off < 1024; off <<= 1) {
    int v = (t >= off) ? part[t - off] : 0;
    __syncthreads();
    part[t] += v;
    __syncthreads();
  }
  int run = part[t] - s;
  for (int i = lo; i < hi; ++i) { rowptr[i] = run; fill[i] = run; run += cnt[i]; }
  if (t == 0) rowptr[N_] = E_;
}

// scatter: CSR-order srcs AND edge_attr (so agg reads both coalesced, twice)
__global__ void scatter_kernel(const int* __restrict__ src, const int* __restrict__ dst,
                               int* __restrict__ fill, const float* __restrict__ edge_attr,
                               int* __restrict__ srcs, float* __restrict__ eattr_s, int E_) {
  int e = blockIdx.x * blockDim.x + threadIdx.x;
  if (e < E_) {
    int pos = atomicAdd(&fill[dst[e]], 1);
    srcs[pos] = src[e];
    const float4* ep = (const float4*)(edge_attr + (size_t)e * NH);
    float4 a0 = ep[0], a1 = ep[1];
    float4* op = (float4*)(eattr_s + (size_t)pos * NH);
    op[0] = a0; op[1] = a1;
  }
}

// ---- fold: M_l[8x8] = We_l x a_e_l ; P_ls/P_ld[32x8] = W_l x a_{src/dst}_l ----
// Mbuf floats: [0:64) M1 | [64:128) M2 | [128:384) P1s | [384:640) P1d
//              | [640:896) P2s | [896:1152) P2d
__global__ void fold_kernel(const float* __restrict__ We1, const float* __restrict__ ae1,
                            const float* __restrict__ We2, const float* __restrict__ ae2,
                            const float* __restrict__ W1, const float* __restrict__ as1,
                            const float* __restrict__ ad1,
                            const float* __restrict__ W2, const float* __restrict__ as2,
                            const float* __restrict__ ad2,
                            float* __restrict__ M) {
  for (int idx = threadIdx.x; idx < 1152; idx += 256) {
    const float* A; const float* V; int i;
    if (idx < 64)       { i = idx;       A = We1; V = ae1; }
    else if (idx < 128) { i = idx - 64;  A = We2; V = ae2; }
    else if (idx < 384) { i = idx - 128; A = W1;  V = as1; }
    else if (idx < 640) { i = idx - 384; A = W1;  V = ad1; }
    else if (idx < 896) { i = idx - 640; A = W2;  V = as2; }
    else                { i = idx - 896; A = W2;  V = ad2; }
    int k = i >> 3, h = i & 7;
    float s = 0.f;
    for (int c = 0; c < FIN; ++c)
      s = fmaf(A[k * HC + h * FIN + c], V[h * FIN + c], s);
    M[idx] = s;
  }
}

// ---- layer-1 prep: xq1 = bf16(emb[node_ids]); alsrc1/aldst1 = x @ P1 --------
__global__ __launch_bounds__(256) void
prep1_kernel(const float* __restrict__ emb, const int* __restrict__ node_ids,
             const float* __restrict__ P,
             bf16* __restrict__ xq, float* __restrict__ alsrc,
             float* __restrict__ aldst, int N_) {
  __shared__ float xs[8][33];
  int t = threadIdx.x, n0 = blockIdx.x * 8;
  int nl = t >> 5, c = t & 31;
  int n = n0 + nl;
  if (n < N_) {
    float v = emb[(size_t)node_ids[n] * FIN + c];
    xq[(size_t)n * FIN + c] = __float2bfloat16(v);
    xs[nl][c] = v;
  }
  __syncthreads();
  if (t < 64) {
    int nl2 = t >> 3, h = t & 7;
    int n2 = n0 + nl2;
    if (n2 < N_) {
      float sa = 0.f, sd = 0.f;
#pragma unroll
      for (int k = 0; k < FIN; ++k) {
        float x = xs[nl2][k];
        sa = fmaf(x, P[k * 8 + h], sa);
        sd = fmaf(x, P[256 + k * 8 + h], sd);
      }
      alsrc[(size_t)n2 * NH + h] = sa;
      aldst[(size_t)n2 * NH + h] = sd;
    }
  }
}

// ---- fused agg: conflict-free LDS staging, 4-ch/thread FMA, batched epilogue
// thread map (FMA): slot = t>>6 (edge subset), l = t&63, h = l>>3, q = l&7
// thread (slot,h,q) accumulates z[h][4q..4q+3] over edges le%4==slot.
template <int K, int LOG2K, bool LOGITS>
__global__ __launch_bounds__(256) void
agg_kernel(const int* __restrict__ rowptr, const int* __restrict__ srcs,
           const float* __restrict__ eattr,
           const float* __restrict__ Mg,
           const float* __restrict__ alsrc, const float* __restrict__ aldst,
           const bf16* __restrict__ xq,
           const float* __restrict__ W, const float* __restrict__ b,
           const float* __restrict__ Wlin, const float* __restrict__ blin,
           float* __restrict__ xoutf, bf16* __restrict__ xqn,
           const float* __restrict__ Pn,
           float* __restrict__ alsrcn, float* __restrict__ aldstn, int N_) {
  __shared__ __align__(16) char smem[17920];
  unsigned int* xsu = (unsigned int*)smem;        // [CAP*16] packed bf16 (8 KB)
  float* wsf    = (float*)(smem + 8192);          // [CAP][8] transposed (4 KB)
  float4* red4  = (float4*)smem;                  // [1024] combine pool (16 KB)
  float* Ms     = (float*)(smem + 16384);         // 64
  float* ald_s  = (float*)(smem + 16640);         // 32
  float* denred = (float*)(smem + 16768);         // [4 slots][4 nodes][8 h]
  float* den_s  = (float*)(smem + 17280);         // [4][8]
  float* xrow   = (float*)(smem + 17408);         // GROUP*32

  int t = threadIdx.x;
  int n0 = blockIdx.x * GROUP;
  int slot = t >> 6, l = t & 63, h = l >> 3, q = l & 7;

  int rp[GROUP + 1];
#pragma unroll
  for (int i = 0; i <= GROUP; ++i) {
    int nn = n0 + i;
    rp[i] = rowptr[(nn <= N_) ? nn : N_];
  }
  if (t < 64) Ms[t] = Mg[t];
  if (t < GROUP * NH) {
    int nn = n0 + (t >> 3);
    ald_s[t] = (nn < N_) ? aldst[(size_t)nn * NH + (t & 7)] : 0.f;
  }
  __syncthreads();

  float4 acc[GROUP];
  float dn[GROUP];
#pragma unroll
  for (int i = 0; i < GROUP; ++i) { acc[i] = make_float4(0.f, 0.f, 0.f, 0.f); dn[i] = 0.f; }

  int beg = rp[0], end = rp[GROUP];
  for (int cbeg = beg; cbeg < end; cbeg += CAP) {
    int clen = end - cbeg; if (clen > CAP) clen = CAP;

    // stage x rows packed (8 lanes/edge, b64 each) -> linear, conflict-free
    int ntask = clen * 8;
    for (int idx = t; idx < ntask; idx += 256) {
      int e = idx >> 3, c4 = idx & 7;
      int s = srcs[cbeg + e];
      uint2 v = *(const uint2*)(xq + (size_t)s * FIN + c4 * 4);
      *(uint2*)&xsu[e * 16 + c4 * 2] = v;
    }
    // stage ex: 2 threads/edge, coalesced eattr float4, float4 LDS writes
    {
      int e2 = t >> 1, half = t & 1;
      if (e2 < clen) {
        int j = cbeg + e2;
        int ii = 0;
        while (j >= rp[ii + 1]) ++ii;
        int sn = srcs[j];
        float4 eah = *(const float4*)(eattr + (size_t)j * NH + half * 4);
        float4 ash = *(const float4*)(alsrc + (size_t)sn * NH + half * 4);
        float eaf[4] = {eah.x, eah.y, eah.z, eah.w};
        float ea[8];
#pragma unroll
        for (int c = 0; c < 4; ++c) {
          float other = __shfl_xor(eaf[c], 1, 64);
          ea[half * 4 + c] = eaf[c];
          ea[(1 - half) * 4 + c] = other;
        }
        float asf[4] = {ash.x, ash.y, ash.z, ash.w};
        float o[4];
#pragma unroll
        for (int i4 = 0; i4 < 4; ++i4) {
          int hh = half * 4 + i4;
          float al = 0.f;
#pragma unroll
          for (int kk = 0; kk < NH; ++kk) al = fmaf(ea[kk], Ms[kk * NH + hh], al);
          float a = asf[i4] + ald_s[ii * NH + hh] + al;
          a = (a >= 0.f) ? a : 0.2f * a;
          o[i4] = __expf(a);
        }
        *(float4*)&wsf[e2 * 8 + half * 4] = make_float4(o[0], o[1], o[2], o[3]);
      }
    }
    __syncthreads();
    // FMA: 1 b64 x-read + 1 broadcast w-read + 4 FMA per edge per wave
#pragma unroll
    for (int i = 0; i < GROUP; ++i) {
      int lo = rp[i] > cbeg ? rp[i] - cbeg : 0;
      int hi = rp[i + 1] - cbeg; if (hi > clen) hi = clen;
      float4 a = acc[i];
      float d = dn[i];
#pragma unroll 2
      for (int le = lo + slot; le < hi; le += 4) {
        float w = wsf[le * 8 + h];
        uint2 u = *(const uint2*)&xsu[le * 16 + q * 2];
        a.x = fmaf(blo(u.x), w, a.x);
        a.y = fmaf(bhi(u.x), w, a.y);
        a.z = fmaf(blo(u.y), w, a.z);
        a.w = fmaf(bhi(u.y), w, a.w);
        d += w;
      }
      acc[i] = a; dn[i] = d;
    }
    __syncthreads();
  }

  // stash slot-partials
  if (q == 0) {
#pragma unroll
    for (int i = 0; i < GROUP; ++i) denred[slot * 32 + i * 8 + h] = dn[i];
  }
#pragma unroll
  for (int i = 0; i < GROUP; ++i) red4[i * 256 + t] = acc[i];
  __syncthreads();

  // denominators (32 threads) while everyone combines slot-partials
  if (t < 32) {
    int i = t >> 3, hh = t & 7;
    float d = denred[i * 8 + hh] + denred[32 + i * 8 + hh] +
              denred[64 + i * 8 + hh] + denred[96 + i * 8 + hh];
    den_s[t] = 1.0f / (d + 1e-16f);
  }
  int i2 = t >> 6, l2 = t & 63;
  float4 r0 = red4[i2 * 256 + l2];
  float4 r1 = red4[i2 * 256 + 64 + l2];
  float4 r2 = red4[i2 * 256 + 128 + l2];
  float4 r3 = red4[i2 * 256 + 192 + l2];
  __syncthreads();
  float rden = den_s[i2 * 8 + (l2 >> 3)];
  float4 z = make_float4((r0.x + r1.x + r2.x + r3.x) * rden,
                         (r0.y + r1.y + r2.y + r3.y) * rden,
                         (r0.z + r1.z + r2.z + r3.z) * rden,
                         (r0.w + r1.w + r2.w + r3.w) * rden);
  float* zs  = (float*)smem;            // GROUP*256 (aliases red4; reads done)
  float* gs  = (float*)(smem + 4096);
  float* red = (float*)(smem + 8192);
  *(float4*)&zs[i2 * 256 + l2 * 4] = z; // channel = (l2>>3)*32 + (l2&7)*4 = 4*l2
  __syncthreads();

  // g = relu(z @ W + b): W column loaded once, reused x GROUP
  int hE = t >> 5;
  float g[GROUP];
#pragma unroll
  for (int i = 0; i < GROUP; ++i) g[i] = b[t];
#pragma unroll
  for (int k4 = 0; k4 < 8; ++k4) {
    float za[GROUP][4];
#pragma unroll
    for (int i = 0; i < GROUP; ++i)
      *(float4*)za[i] = *(const float4*)&zs[i * 256 + hE * 32 + k4 * 4];
#pragma unroll
    for (int kk = 0; kk < 4; ++kk) {
      float wv = W[(k4 * 4 + kk) * HC + t];
#pragma unroll
      for (int i = 0; i < GROUP; ++i) g[i] = fmaf(za[i][kk], wv, g[i]);
    }
  }
#pragma unroll
  for (int i = 0; i < GROUP; ++i) gs[i * 256 + t] = (g[i] > 0.f) ? g[i] : 0.f;
  __syncthreads();

  // lin: xout = g @ Wlin + blin (Wlin element reused x GROUP)
  {
    int kk = t & (K - 1), r = t >> LOG2K;
    float part[GROUP];
#pragma unroll
    for (int i = 0; i < GROUP; ++i) part[i] = 0.f;
#pragma unroll
    for (int j4 = 0; j4 < K / 4; ++j4) {
      float ga[GROUP][4];
#pragma unroll
      for (int i = 0; i < GROUP; ++i)
        *(float4*)ga[i] = *(const float4*)&gs[i * 256 + r * K + j4 * 4];
#pragma unroll
      for (int jj = 0; jj < 4; ++jj) {
        float wl = Wlin[(r * K + j4 * 4 + jj) * K + kk];
#pragma unroll
        for (int i = 0; i < GROUP; ++i) part[i] = fmaf(ga[i][jj], wl, part[i]);
      }
    }
#pragma unroll
    for (int i = 0; i < GROUP; ++i) red[i * 256 + t] = part[i];
  }
  __syncthreads();

  if (LOGITS) {
    if (t < GROUP * 32) {
      int i = t >> 5, kk = t & 31;
      float s = blin[kk];
#pragma unroll
      for (int r2 = 0; r2 < HC / K; ++r2) s += red[i * 256 + r2 * K + kk];
      int nn = n0 + i;
      if (nn < N_) xqn[(size_t)nn * FIN + kk] = __float2bfloat16(s);
      xrow[t] = s;
    }
    __syncthreads();
    if (t < GROUP * NH) {
      int i = t >> 3, hh = t & 7;
      int nn = n0 + i;
      if (nn < N_) {
        float sa = 0.f, sd = 0.f;
#pragma unroll
        for (int k2 = 0; k2 < FIN; ++k2) {
          float x = xrow[i * 32 + k2];
          sa = fmaf(x, Pn[k2 * 8 + hh], sa);
          sd = fmaf(x, Pn[256 + k2 * 8 + hh], sd);
        }
        alsrcn[(size_t)nn * NH + hh] = sa;
        aldstn[(size_t)nn * NH + hh] = sd;
      }
    }
  } else {
    if (t < GROUP * K) {
      int i = t >> LOG2K, kk = t & (K - 1);
      float s = blin[kk];
#pragma unroll
      for (int r2 = 0; r2 < HC / K; ++r2) s += red[i * 256 + r2 * K + kk];
      int nn = n0 + i;
      if (nn < N_) xoutf[(size_t)nn * K + kk] = s;
    }
  }
}

// ---------------- classifier: sigmoid(sum(fu*fm)) ----------------------------
__global__ void clf_kernel(const int* __restrict__ eli, const float* __restrict__ ela,
                           const float* __restrict__ x2, const float* __restrict__ clfW,
                           const float* __restrict__ clfb, float* __restrict__ out, int L_) {
  int i = blockIdx.x * blockDim.x + threadIdx.x;
  if (i >= L_) return;
  int u = eli[i], m = eli[L_ + i];
  const float4* xup = (const float4*)(x2 + (size_t)u * NH);
  const float4* xmp = (const float4*)(x2 + (size_t)m * NH);
  const float4* eap = (const float4*)(ela + (size_t)i * NH);
  float4 xu0 = xup[0], xu1 = xup[1];
  float4 xm0 = xmp[0], xm1 = xmp[1];
  float4 el0 = eap[0], el1 = eap[1];
  float xu[NH] = {xu0.x, xu0.y, xu0.z, xu0.w, xu1.x, xu1.y, xu1.z, xu1.w};
  float xm[NH] = {xm0.x, xm0.y, xm0.z, xm0.w, xm1.x, xm1.y, xm1.z, xm1.w};
  float el[NH] = {el0.x, el0.y, el0.z, el0.w, el1.x, el1.y, el1.z, el1.w};
  float fu[NH];
#pragma unroll
  for (int kk = 0; kk < NH; ++kk) fu[kk] = clfb[kk];
#pragma unroll
  for (int j = 0; j < NH; ++j) {
#pragma unroll
    for (int kk = 0; kk < NH; ++kk) fu[kk] = fmaf(xu[j], clfW[j * NH + kk], fu[kk]);
  }
#pragma unroll
  for (int j = 0; j < NH; ++j) {
#pragma unroll
    for (int kk = 0; kk < NH; ++kk) fu[kk] = fmaf(el[j], clfW[(NH + j) * NH + kk], fu[kk]);
  }
  float dot = 0.f;
#pragma unroll
  for (int kk = 0; kk < NH; ++kk) dot += fu[kk] * xm[kk];
  out[i] = 1.f / (1.f + expf(-dot));
}

extern "C" void kernel_launch(void* const* d_in, const int* in_sizes, int n_in,
                              void* d_out, int out_size, void* d_ws, size_t ws_size,
                              hipStream_t stream) {
  const int* node_ids   = (const int*)d_in[0];
  const int* edge_index = (const int*)d_in[1];
  const int* eli        = (const int*)d_in[2];
  const float* edge_attr = (const float*)d_in[4];
  const float* ela       = (const float*)d_in[5];
  const float* emb       = (const float*)d_in[6];
  const float* W1     = (const float*)d_in[7];
  const float* a_src1 = (const float*)d_in[8];
  const float* a_dst1 = (const float*)d_in[9];
  const float* We1    = (const float*)d_in[10];
  const float* a_e1   = (const float*)d_in[11];
  const float* b1     = (const float*)d_in[12];
  const float* lin1W  = (const float*)d_in[13];
  const float* lin1b  = (const float*)d_in[14];
  const float* W2     = (const float*)d_in[15];
  const float* a_src2 = (const float*)d_in[16];
  const float* a_dst2 = (const float*)d_in[17];
  const float* We2    = (const float*)d_in[18];
  const float* a_e2   = (const float*)d_in[19];
  const float* b2     = (const float*)d_in[20];
  const float* lin5W  = (const float*)d_in[21];
  const float* lin5b  = (const float*)d_in[22];
  const float* clfW   = (const float*)d_in[23];
  const float* clfb   = (const float*)d_in[24];

  const int N_ = in_sizes[0];
  const int E_ = in_sizes[1] / 2;
  const int L_ = in_sizes[2] / 2;
  const int* src  = edge_index;
  const int* dstp = edge_index + E_;

  char* p = (char*)d_ws;
  auto carve = [&](size_t bytes) -> char* {
    char* r = p;
    p += (bytes + 255) & ~(size_t)255;
    return r;
  };
  bf16*  xq1     = (bf16*)carve((size_t)N_ * FIN * 2);
  bf16*  xq2     = (bf16*)carve((size_t)N_ * FIN * 2);
  float* eattr_s = (float*)carve((size_t)E_ * NH * 4);   // 25.6 MB CSR-ordered
  float* alsrc1  = (float*)carve((size_t)N_ * NH * 4);
  float* aldst1  = (float*)carve((size_t)N_ * NH * 4);
  float* alsrc2  = (float*)carve((size_t)N_ * NH * 4);
  float* aldst2  = (float*)carve((size_t)N_ * NH * 4);
  float* x2b     = (float*)carve((size_t)N_ * NH * 4);
  float* Mbuf    = (float*)carve(1152 * 4);
  int*   cnt     = (int*)carve((size_t)N_ * 4);
  int*   rowptr  = (int*)carve((size_t)(N_ + 1) * 4);
  int*   fill    = (int*)carve((size_t)N_ * 4);
  int*   srcs    = (int*)carve((size_t)E_ * 4);

  hipMemsetAsync(cnt, 0, (size_t)N_ * 4, stream);
  int eb = (E_ + 255) / 256;
  fold_kernel<<<1, 256, 0, stream>>>(We1, a_e1, We2, a_e2, W1, a_src1, a_dst1,
                                     W2, a_src2, a_dst2, Mbuf);
  count_kernel<<<eb, 256, 0, stream>>>(dstp, cnt, E_);
  scan_kernel<<<1, 1024, 0, stream>>>(cnt, rowptr, fill, N_, E_);
  scatter_kernel<<<eb, 256, 0, stream>>>(src, dstp, fill, edge_attr, srcs, eattr_s, E_);
  prep1_kernel<<<(N_ + 7) / 8, 256, 0, stream>>>(emb, node_ids, Mbuf + 128,
                                                 xq1, alsrc1, aldst1, N_);

  int gb = (N_ + GROUP - 1) / GROUP;
  // ---- layer 1 (fully fused) ----
  agg_kernel<32, 5, true><<<gb, 256, 0, stream>>>(
      rowptr, srcs, eattr_s, Mbuf, alsrc1, aldst1, xq1,
      W1, b1, lin1W, lin1b, nullptr, xq2, Mbuf + 640, alsrc2, aldst2, N_);

  // ---- layer 2 ----
  agg_kernel<8, 3, false><<<gb, 256, 0, stream>>>(
      rowptr, srcs, eattr_s, Mbuf + 64, alsrc2, aldst2, xq2,
      W2, b2, lin5W, lin5b, x2b, nullptr, nullptr, nullptr, nullptr, N_);

  // ---- classifier ----
  clf_kernel<<<(L_ + 255) / 256, 256, 0, stream>>>(eli, ela, x2b, clfW, clfb,
                                                   (float*)d_out, L_);
}

// Round 11
// 404.740 us; speedup vs baseline: 1.9480x; 1.2388x over previous
//
#include <hip/hip_runtime.h>
#include <hip/hip_bf16.h>

#define HC    256
#define FIN   32
#define NH    8
#define GROUP 4     // dst nodes per block
#define CAP   128   // staged edges per chunk

typedef __hip_bfloat16 bf16;

__device__ __forceinline__ float blo(unsigned int u) { return __uint_as_float(u << 16); }
__device__ __forceinline__ float bhi(unsigned int u) { return __uint_as_float(u & 0xffff0000u); }

// ---------------- CSR build ---------------------------------------------------
__global__ void count_kernel(const int* __restrict__ dst, int* __restrict__ cnt, int E_) {
  int e = blockIdx.x * blockDim.x + threadIdx.x;
  if (e < E_) atomicAdd(&cnt[dst[e]], 1);
}

// multi-block scan, step 1: per-256-tile inclusive prefix (into tmp) + block sums
__global__ __launch_bounds__(256) void
scan_partial(const int* __restrict__ cnt, int* __restrict__ tmp,
             int* __restrict__ bsum, int N_) {
  __shared__ int part[256];
  int t = threadIdx.x, i = blockIdx.x * 256 + t;
  int v = (i < N_) ? cnt[i] : 0;
  part[t] = v;
  __syncthreads();
#pragma unroll
  for (int off = 1; off < 256; off <<= 1) {
    int u = (t >= off) ? part[t - off] : 0;
    __syncthreads();
    part[t] += u;
    __syncthreads();
  }
  if (i < N_) tmp[i] = part[t];
  if (t == 255) bsum[blockIdx.x] = part[255];
}

// step 2: exclusive scan of block sums (<=1024 blocks)
__global__ __launch_bounds__(1024) void
scan_bsum(int* __restrict__ bsum, int NB) {
  __shared__ int part[1024];
  int t = threadIdx.x;
  int v = (t < NB) ? bsum[t] : 0;
  part[t] = v;
  __syncthreads();
  for (int off = 1; off < 1024; off <<= 1) {
    int u = (t >= off) ? part[t - off] : 0;
    __syncthreads();
    part[t] += u;
    __syncthreads();
  }
  if (t < NB) bsum[t] = part[t] - v;   // exclusive
}

// step 3: rowptr[i] = boff[blk] + incl[i] - cnt[i]; fill = rowptr; rowptr[N]=E
__global__ __launch_bounds__(256) void
scan_final(const int* __restrict__ cnt, const int* __restrict__ tmp,
           const int* __restrict__ bsum, int* __restrict__ rowptr,
           int* __restrict__ fill, int N_, int E_) {
  int t = threadIdx.x, i = blockIdx.x * 256 + t;
  if (i < N_) {
    int ex = bsum[blockIdx.x] + tmp[i] - cnt[i];
    rowptr[i] = ex;
    fill[i] = ex;
  }
  if (i == 0) rowptr[N_] = E_;
}

// scatter: CSR-order srcs AND edge_attr (so agg reads both coalesced, twice)
__global__ void scatter_kernel(const int* __restrict__ src, const int* __restrict__ dst,
                               int* __restrict__ fill, const float* __restrict__ edge_attr,
                               int* __restrict__ srcs, float* __restrict__ eattr_s, int E_) {
  int e = blockIdx.x * blockDim.x + threadIdx.x;
  if (e < E_) {
    int pos = atomicAdd(&fill[dst[e]], 1);
    srcs[pos] = src[e];
    const float4* ep = (const float4*)(edge_attr + (size_t)e * NH);
    float4 a0 = ep[0], a1 = ep[1];
    float4* op = (float4*)(eattr_s + (size_t)pos * NH);
    op[0] = a0; op[1] = a1;
  }
}

// ---- fold: M_l[8x8] = We_l x a_e_l ; P_ls/P_ld[32x8] = W_l x a_{src/dst}_l ----
// Mbuf floats: [0:64) M1 | [64:128) M2 | [128:384) P1s | [384:640) P1d
//              | [640:896) P2s | [896:1152) P2d
__global__ void fold_kernel(const float* __restrict__ We1, const float* __restrict__ ae1,
                            const float* __restrict__ We2, const float* __restrict__ ae2,
                            const float* __restrict__ W1, const float* __restrict__ as1,
                            const float* __restrict__ ad1,
                            const float* __restrict__ W2, const float* __restrict__ as2,
                            const float* __restrict__ ad2,
                            float* __restrict__ M) {
  for (int idx = threadIdx.x; idx < 1152; idx += 256) {
    const float* A; const float* V; int i;
    if (idx < 64)       { i = idx;       A = We1; V = ae1; }
    else if (idx < 128) { i = idx - 64;  A = We2; V = ae2; }
    else if (idx < 384) { i = idx - 128; A = W1;  V = as1; }
    else if (idx < 640) { i = idx - 384; A = W1;  V = ad1; }
    else if (idx < 896) { i = idx - 640; A = W2;  V = as2; }
    else                { i = idx - 896; A = W2;  V = ad2; }
    int k = i >> 3, h = i & 7;
    float s = 0.f;
    for (int c = 0; c < FIN; ++c)
      s = fmaf(A[k * HC + h * FIN + c], V[h * FIN + c], s);
    M[idx] = s;
  }
}

// ---- layer-1 prep: xq1 = bf16(emb[node_ids]); alsrc1/aldst1 = x @ P1 --------
__global__ __launch_bounds__(256) void
prep1_kernel(const float* __restrict__ emb, const int* __restrict__ node_ids,
             const float* __restrict__ P,
             bf16* __restrict__ xq, float* __restrict__ alsrc,
             float* __restrict__ aldst, int N_) {
  __shared__ float xs[8][33];
  int t = threadIdx.x, n0 = blockIdx.x * 8;
  int nl = t >> 5, c = t & 31;
  int n = n0 + nl;
  if (n < N_) {
    float v = emb[(size_t)node_ids[n] * FIN + c];
    xq[(size_t)n * FIN + c] = __float2bfloat16(v);
    xs[nl][c] = v;
  }
  __syncthreads();
  if (t < 64) {
    int nl2 = t >> 3, h = t & 7;
    int n2 = n0 + nl2;
    if (n2 < N_) {
      float sa = 0.f, sd = 0.f;
#pragma unroll
      for (int k = 0; k < FIN; ++k) {
        float x = xs[nl2][k];
        sa = fmaf(x, P[k * 8 + h], sa);
        sd = fmaf(x, P[256 + k * 8 + h], sd);
      }
      alsrc[(size_t)n2 * NH + h] = sa;
      aldst[(size_t)n2 * NH + h] = sd;
    }
  }
}

// ---- fused agg: conflict-free LDS staging, 4-ch/thread FMA, batched epilogue
// thread map (FMA): slot = t>>6 (edge subset), l = t&63, h = l>>3, q = l&7
// thread (slot,h,q) accumulates z[h][4q..4q+3] over edges le%4==slot.
template <int K, int LOG2K, bool LOGITS>
__global__ __launch_bounds__(256) void
agg_kernel(const int* __restrict__ rowptr, const int* __restrict__ srcs,
           const float* __restrict__ eattr,
           const float* __restrict__ Mg,
           const float* __restrict__ alsrc, const float* __restrict__ aldst,
           const bf16* __restrict__ xq,
           const float* __restrict__ W, const float* __restrict__ b,
           const float* __restrict__ Wlin, const float* __restrict__ blin,
           float* __restrict__ xoutf, bf16* __restrict__ xqn,
           const float* __restrict__ Pn,
           float* __restrict__ alsrcn, float* __restrict__ aldstn, int N_) {
  __shared__ __align__(16) char smem[17920];
  unsigned int* xsu = (unsigned int*)smem;        // [CAP*16] packed bf16 (8 KB)
  float* wsf    = (float*)(smem + 8192);          // [CAP][8] transposed (4 KB)
  float4* red4  = (float4*)smem;                  // [1024] combine pool (16 KB)
  float* Ms     = (float*)(smem + 16384);         // 64
  float* ald_s  = (float*)(smem + 16640);         // 32
  float* denred = (float*)(smem + 16768);         // [4 slots][4 nodes][8 h]
  float* den_s  = (float*)(smem + 17280);         // [4][8]
  float* xrow   = (float*)(smem + 17408);         // GROUP*32

  int t = threadIdx.x;
  int n0 = blockIdx.x * GROUP;
  int slot = t >> 6, l = t & 63, h = l >> 3, q = l & 7;

  int rp[GROUP + 1];
#pragma unroll
  for (int i = 0; i <= GROUP; ++i) {
    int nn = n0 + i;
    rp[i] = rowptr[(nn <= N_) ? nn : N_];
  }
  if (t < 64) Ms[t] = Mg[t];
  if (t < GROUP * NH) {
    int nn = n0 + (t >> 3);
    ald_s[t] = (nn < N_) ? aldst[(size_t)nn * NH + (t & 7)] : 0.f;
  }
  __syncthreads();

  float4 acc[GROUP];
  float dn[GROUP];
#pragma unroll
  for (int i = 0; i < GROUP; ++i) { acc[i] = make_float4(0.f, 0.f, 0.f, 0.f); dn[i] = 0.f; }

  int beg = rp[0], end = rp[GROUP];
  for (int cbeg = beg; cbeg < end; cbeg += CAP) {
    int clen = end - cbeg; if (clen > CAP) clen = CAP;

    // stage x rows packed (8 lanes/edge, b64 each) -> linear, conflict-free
    int ntask = clen * 8;
    for (int idx = t; idx < ntask; idx += 256) {
      int e = idx >> 3, c4 = idx & 7;
      int s = srcs[cbeg + e];
      uint2 v = *(const uint2*)(xq + (size_t)s * FIN + c4 * 4);
      *(uint2*)&xsu[e * 16 + c4 * 2] = v;
    }
    // stage ex: 2 threads/edge, coalesced eattr float4, float4 LDS writes
    {
      int e2 = t >> 1, half = t & 1;
      if (e2 < clen) {
        int j = cbeg + e2;
        int ii = 0;
        while (j >= rp[ii + 1]) ++ii;
        int sn = srcs[j];
        float4 eah = *(const float4*)(eattr + (size_t)j * NH + half * 4);
        float4 ash = *(const float4*)(alsrc + (size_t)sn * NH + half * 4);
        float eaf[4] = {eah.x, eah.y, eah.z, eah.w};
        float ea[8];
#pragma unroll
        for (int c = 0; c < 4; ++c) {
          float other = __shfl_xor(eaf[c], 1, 64);
          ea[half * 4 + c] = eaf[c];
          ea[(1 - half) * 4 + c] = other;
        }
        float asf[4] = {ash.x, ash.y, ash.z, ash.w};
        float o[4];
#pragma unroll
        for (int i4 = 0; i4 < 4; ++i4) {
          int hh = half * 4 + i4;
          float al = 0.f;
#pragma unroll
          for (int kk = 0; kk < NH; ++kk) al = fmaf(ea[kk], Ms[kk * NH + hh], al);
          float a = asf[i4] + ald_s[ii * NH + hh] + al;
          a = (a >= 0.f) ? a : 0.2f * a;
          o[i4] = __expf(a);
        }
        *(float4*)&wsf[e2 * 8 + half * 4] = make_float4(o[0], o[1], o[2], o[3]);
      }
    }
    __syncthreads();
    // FMA: 1 b64 x-read + 1 broadcast w-read + 4 FMA per edge per wave
#pragma unroll
    for (int i = 0; i < GROUP; ++i) {
      int lo = rp[i] > cbeg ? rp[i] - cbeg : 0;
      int hi = rp[i + 1] - cbeg; if (hi > clen) hi = clen;
      float4 a = acc[i];
      float d = dn[i];
#pragma unroll 2
      for (int le = lo + slot; le < hi; le += 4) {
        float w = wsf[le * 8 + h];
        uint2 u = *(const uint2*)&xsu[le * 16 + q * 2];
        a.x = fmaf(blo(u.x), w, a.x);
        a.y = fmaf(bhi(u.x), w, a.y);
        a.z = fmaf(blo(u.y), w, a.z);
        a.w = fmaf(bhi(u.y), w, a.w);
        d += w;
      }
      acc[i] = a; dn[i] = d;
    }
    __syncthreads();
  }

  // stash slot-partials
  if (q == 0) {
#pragma unroll
    for (int i = 0; i < GROUP; ++i) denred[slot * 32 + i * 8 + h] = dn[i];
  }
#pragma unroll
  for (int i = 0; i < GROUP; ++i) red4[i * 256 + t] = acc[i];
  __syncthreads();

  // denominators (32 threads) while everyone combines slot-partials
  if (t < 32) {
    int i = t >> 3, hh = t & 7;
    float d = denred[i * 8 + hh] + denred[32 + i * 8 + hh] +
              denred[64 + i * 8 + hh] + denred[96 + i * 8 + hh];
    den_s[t] = 1.0f / (d + 1e-16f);
  }
  int i2 = t >> 6, l2 = t & 63;
  float4 r0 = red4[i2 * 256 + l2];
  float4 r1 = red4[i2 * 256 + 64 + l2];
  float4 r2 = red4[i2 * 256 + 128 + l2];
  float4 r3 = red4[i2 * 256 + 192 + l2];
  __syncthreads();
  float rden = den_s[i2 * 8 + (l2 >> 3)];
  float4 z = make_float4((r0.x + r1.x + r2.x + r3.x) * rden,
                         (r0.y + r1.y + r2.y + r3.y) * rden,
                         (r0.z + r1.z + r2.z + r3.z) * rden,
                         (r0.w + r1.w + r2.w + r3.w) * rden);
  float* zs  = (float*)smem;            // GROUP*256 (aliases red4; reads done)
  float* gs  = (float*)(smem + 4096);
  float* red = (float*)(smem + 8192);
  *(float4*)&zs[i2 * 256 + l2 * 4] = z; // channel = (l2>>3)*32 + (l2&7)*4 = 4*l2
  __syncthreads();

  // g = relu(z @ W + b): W column loaded once, reused x GROUP
  int hE = t >> 5;
  float g[GROUP];
#pragma unroll
  for (int i = 0; i < GROUP; ++i) g[i] = b[t];
#pragma unroll
  for (int k4 = 0; k4 < 8; ++k4) {
    float za[GROUP][4];
#pragma unroll
    for (int i = 0; i < GROUP; ++i)
      *(float4*)za[i] = *(const float4*)&zs[i * 256 + hE * 32 + k4 * 4];
#pragma unroll
    for (int kk = 0; kk < 4; ++kk) {
      float wv = W[(k4 * 4 + kk) * HC + t];
#pragma unroll
      for (int i = 0; i < GROUP; ++i) g[i] = fmaf(za[i][kk], wv, g[i]);
    }
  }
#pragma unroll
  for (int i = 0; i < GROUP; ++i) gs[i * 256 + t] = (g[i] > 0.f) ? g[i] : 0.f;
  __syncthreads();

  // lin: xout = g @ Wlin + blin (Wlin element reused x GROUP)
  {
    int kk = t & (K - 1), r = t >> LOG2K;
    float part[GROUP];
#pragma unroll
    for (int i = 0; i < GROUP; ++i) part[i] = 0.f;
#pragma unroll
    for (int j4 = 0; j4 < K / 4; ++j4) {
      float ga[GROUP][4];
#pragma unroll
      for (int i = 0; i < GROUP; ++i)
        *(float4*)ga[i] = *(const float4*)&gs[i * 256 + r * K + j4 * 4];
#pragma unroll
      for (int jj = 0; jj < 4; ++jj) {
        float wl = Wlin[(r * K + j4 * 4 + jj) * K + kk];
#pragma unroll
        for (int i = 0; i < GROUP; ++i) part[i] = fmaf(ga[i][jj], wl, part[i]);
      }
    }
#pragma unroll
    for (int i = 0; i < GROUP; ++i) red[i * 256 + t] = part[i];
  }
  __syncthreads();

  if (LOGITS) {
    if (t < GROUP * 32) {
      int i = t >> 5, kk = t & 31;
      float s = blin[kk];
#pragma unroll
      for (int r2 = 0; r2 < HC / K; ++r2) s += red[i * 256 + r2 * K + kk];
      int nn = n0 + i;
      if (nn < N_) xqn[(size_t)nn * FIN + kk] = __float2bfloat16(s);
      xrow[t] = s;
    }
    __syncthreads();
    if (t < GROUP * NH) {
      int i = t >> 3, hh = t & 7;
      int nn = n0 + i;
      if (nn < N_) {
        float sa = 0.f, sd = 0.f;
#pragma unroll
        for (int k2 = 0; k2 < FIN; ++k2) {
          float x = xrow[i * 32 + k2];
          sa = fmaf(x, Pn[k2 * 8 + hh], sa);
          sd = fmaf(x, Pn[256 + k2 * 8 + hh], sd);
        }
        alsrcn[(size_t)nn * NH + hh] = sa;
        aldstn[(size_t)nn * NH + hh] = sd;
      }
    }
  } else {
    if (t < GROUP * K) {
      int i = t >> LOG2K, kk = t & (K - 1);
      float s = blin[kk];
#pragma unroll
      for (int r2 = 0; r2 < HC / K; ++r2) s += red[i * 256 + r2 * K + kk];
      int nn = n0 + i;
      if (nn < N_) xoutf[(size_t)nn * K + kk] = s;
    }
  }
}

// ---------------- classifier: sigmoid(sum(fu*fm)) ----------------------------
__global__ void clf_kernel(const int* __restrict__ eli, const float* __restrict__ ela,
                           const float* __restrict__ x2, const float* __restrict__ clfW,
                           const float* __restrict__ clfb, float* __restrict__ out, int L_) {
  int i = blockIdx.x * blockDim.x + threadIdx.x;
  if (i >= L_) return;
  int u = eli[i], m = eli[L_ + i];
  const float4* xup = (const float4*)(x2 + (size_t)u * NH);
  const float4* xmp = (const float4*)(x2 + (size_t)m * NH);
  const float4* eap = (const float4*)(ela + (size_t)i * NH);
  float4 xu0 = xup[0], xu1 = xup[1];
  float4 xm0 = xmp[0], xm1 = xmp[1];
  float4 el0 = eap[0], el1 = eap[1];
  float xu[NH] = {xu0.x, xu0.y, xu0.z, xu0.w, xu1.x, xu1.y, xu1.z, xu1.w};
  float xm[NH] = {xm0.x, xm0.y, xm0.z, xm0.w, xm1.x, xm1.y, xm1.z, xm1.w};
  float el[NH] = {el0.x, el0.y, el0.z, el0.w, el1.x, el1.y, el1.z, el1.w};
  float fu[NH];
#pragma unroll
  for (int kk = 0; kk < NH; ++kk) fu[kk] = clfb[kk];
#pragma unroll
  for (int j = 0; j < NH; ++j) {
#pragma unroll
    for (int kk = 0; kk < NH; ++kk) fu[kk] = fmaf(xu[j], clfW[j * NH + kk], fu[kk]);
  }
#pragma unroll
  for (int j = 0; j < NH; ++j) {
#pragma unroll
    for (int kk = 0; kk < NH; ++kk) fu[kk] = fmaf(el[j], clfW[(NH + j) * NH + kk], fu[kk]);
  }
  float dot = 0.f;
#pragma unroll
  for (int kk = 0; kk < NH; ++kk) dot += fu[kk] * xm[kk];
  out[i] = 1.f / (1.f + expf(-dot));
}

extern "C" void kernel_launch(void* const* d_in, const int* in_sizes, int n_in,
                              void* d_out, int out_size, void* d_ws, size_t ws_size,
                              hipStream_t stream) {
  const int* node_ids   = (const int*)d_in[0];
  const int* edge_index = (const int*)d_in[1];
  const int* eli        = (const int*)d_in[2];
  const float* edge_attr = (const float*)d_in[4];
  const float* ela       = (const float*)d_in[5];
  const float* emb       = (const float*)d_in[6];
  const float* W1     = (const float*)d_in[7];
  const float* a_src1 = (const float*)d_in[8];
  const float* a_dst1 = (const float*)d_in[9];
  const float* We1    = (const float*)d_in[10];
  const float* a_e1   = (const float*)d_in[11];
  const float* b1     = (const float*)d_in[12];
  const float* lin1W  = (const float*)d_in[13];
  const float* lin1b  = (const float*)d_in[14];
  const float* W2     = (const float*)d_in[15];
  const float* a_src2 = (const float*)d_in[16];
  const float* a_dst2 = (const float*)d_in[17];
  const float* We2    = (const float*)d_in[18];
  const float* a_e2   = (const float*)d_in[19];
  const float* b2     = (const float*)d_in[20];
  const float* lin5W  = (const float*)d_in[21];
  const float* lin5b  = (const float*)d_in[22];
  const float* clfW   = (const float*)d_in[23];
  const float* clfb   = (const float*)d_in[24];

  const int N_ = in_sizes[0];
  const int E_ = in_sizes[1] / 2;
  const int L_ = in_sizes[2] / 2;
  const int* src  = edge_index;
  const int* dstp = edge_index + E_;

  char* p = (char*)d_ws;
  auto carve = [&](size_t bytes) -> char* {
    char* r = p;
    p += (bytes + 255) & ~(size_t)255;
    return r;
  };
  bf16*  xq1     = (bf16*)carve((size_t)N_ * FIN * 2);
  bf16*  xq2     = (bf16*)carve((size_t)N_ * FIN * 2);
  float* eattr_s = (float*)carve((size_t)E_ * NH * 4);   // 25.6 MB CSR-ordered
  float* alsrc1  = (float*)carve((size_t)N_ * NH * 4);
  float* aldst1  = (float*)carve((size_t)N_ * NH * 4);
  float* alsrc2  = (float*)carve((size_t)N_ * NH * 4);
  float* aldst2  = (float*)carve((size_t)N_ * NH * 4);
  float* x2b     = (float*)carve((size_t)N_ * NH * 4);
  float* Mbuf    = (float*)carve(1152 * 4);
  int*   cnt     = (int*)carve((size_t)N_ * 4);
  int*   rowptr  = (int*)carve((size_t)(N_ + 1) * 4);
  int*   fill    = (int*)carve((size_t)N_ * 4);
  int*   stmp    = (int*)carve((size_t)N_ * 4);
  int*   bsum    = (int*)carve(1024 * 4);
  int*   srcs    = (int*)carve((size_t)E_ * 4);

  hipMemsetAsync(cnt, 0, (size_t)N_ * 4, stream);
  int eb = (E_ + 255) / 256;
  int nb = (N_ + 255) / 256;
  fold_kernel<<<1, 256, 0, stream>>>(We1, a_e1, We2, a_e2, W1, a_src1, a_dst1,
                                     W2, a_src2, a_dst2, Mbuf);
  count_kernel<<<eb, 256, 0, stream>>>(dstp, cnt, E_);
  scan_partial<<<nb, 256, 0, stream>>>(cnt, stmp, bsum, N_);
  scan_bsum<<<1, 1024, 0, stream>>>(bsum, nb);
  scan_final<<<nb, 256, 0, stream>>>(cnt, stmp, bsum, rowptr, fill, N_, E_);
  scatter_kernel<<<eb, 256, 0, stream>>>(src, dstp, fill, edge_attr, srcs, eattr_s, E_);
  prep1_kernel<<<(N_ + 7) / 8, 256, 0, stream>>>(emb, node_ids, Mbuf + 128,
                                                 xq1, alsrc1, aldst1, N_);

  int gb = (N_ + GROUP - 1) / GROUP;
  // ---- layer 1 (fully fused) ----
  agg_kernel<32, 5, true><<<gb, 256, 0, stream>>>(
      rowptr, srcs, eattr_s, Mbuf, alsrc1, aldst1, xq1,
      W1, b1, lin1W, lin1b, nullptr, xq2, Mbuf + 640, alsrc2, aldst2, N_);

  // ---- layer 2 ----
  agg_kernel<8, 3, false><<<gb, 256, 0, stream>>>(
      rowptr, srcs, eattr_s, Mbuf + 64, alsrc2, aldst2, xq2,
      W2, b2, lin5W, lin5b, x2b, nullptr, nullptr, nullptr, nullptr, N_);

  // ---- classifier ----
  clf_kernel<<<(L_ + 255) / 256, 256, 0, stream>>>(eli, ela, x2b, clfW, clfb,
                                                   (float*)d_out, L_);
}